// Round 1
// baseline (6928.016 us; speedup 1.0000x reference)
//
#include <hip/hip_runtime.h>
#include <cstddef>

#define E_TOTAL 3200000
#define N_NODES 100000
#define N_RELS 50
#define N_BASES 16
#define HD 16
#define OD 8
#define NBLK 2560
#define NTHR 256

__device__ __forceinline__ void fma4(float* acc, float c, float4 w) {
    acc[0] = fmaf(c, w.x, acc[0]);
    acc[1] = fmaf(c, w.y, acc[1]);
    acc[2] = fmaf(c, w.z, acc[2]);
    acc[3] = fmaf(c, w.w, acc[3]);
}

// Wr1[r,i,o] = sum_b C1[r,b] * W1[b,i,o]   (50x16x16)
// Wr2[r,i,o] = sum_b C2[r,b] * W2[b,i,o]   (50x16x8)
__global__ __launch_bounds__(NTHR) void k_wr(const float* __restrict__ W1, const float* __restrict__ C1,
                                             const float* __restrict__ W2, const float* __restrict__ C2,
                                             float* __restrict__ Wr1, float* __restrict__ Wr2) {
    int idx = blockIdx.x * NTHR + threadIdx.x;
    const int n1 = N_RELS * 256;
    if (idx < n1) {
        int r = idx >> 8, io = idx & 255;
        float acc = 0.f;
        #pragma unroll
        for (int b = 0; b < N_BASES; ++b)
            acc = fmaf(C1[r * N_BASES + b], W1[b * 256 + io], acc);
        Wr1[idx] = acc;
    } else if (idx < n1 + N_RELS * 128) {
        int j = idx - n1;
        int r = j >> 7, io = j & 127;
        float acc = 0.f;
        #pragma unroll
        for (int b = 0; b < N_BASES; ++b)
            acc = fmaf(C2[r * N_BASES + b], W2[b * 128 + io], acc);
        Wr2[j] = acc;
    }
}

// Layer 0: h0[dst] += norm * sum_b C0[rel,b] * W0[b, src, :]
__global__ __launch_bounds__(NTHR) void k_l0(const int* __restrict__ esrc, const int* __restrict__ edst,
                                             const int* __restrict__ erel, const float* __restrict__ enorm,
                                             const float* __restrict__ W0, const float* __restrict__ C0,
                                             float* __restrict__ h0) {
    for (int e = blockIdx.x * NTHR + threadIdx.x; e < E_TOTAL; e += NBLK * NTHR) {
        int s = esrc[e], d = edst[e], r = erel[e];
        float nm = enorm[e];
        const float4* cp = reinterpret_cast<const float4*>(C0 + r * N_BASES);
        float4 c0 = cp[0], c1 = cp[1], c2 = cp[2], c3 = cp[3];
        float coef[16] = {c0.x, c0.y, c0.z, c0.w, c1.x, c1.y, c1.z, c1.w,
                          c2.x, c2.y, c2.z, c2.w, c3.x, c3.y, c3.z, c3.w};
        float acc[16];
        #pragma unroll
        for (int h = 0; h < 16; ++h) acc[h] = 0.f;
        const float* wbase = W0 + (size_t)s * HD;
        #pragma unroll
        for (int b = 0; b < N_BASES; ++b) {
            const float4* wp = reinterpret_cast<const float4*>(wbase + (size_t)b * (N_NODES * HD));
            float4 w0 = wp[0], w1 = wp[1], w2 = wp[2], w3 = wp[3];
            float cb = coef[b];
            fma4(acc + 0, cb, w0);
            fma4(acc + 4, cb, w1);
            fma4(acc + 8, cb, w2);
            fma4(acc + 12, cb, w3);
        }
        float* out = h0 + (size_t)d * HD;
        #pragma unroll
        for (int h = 0; h < 16; ++h) atomicAdd(out + h, nm * acc[h]);
    }
}

// Layer 1: h1[dst] += norm * (relu(h0[src]) @ Wr1[rel])   (16 -> 16)
__global__ __launch_bounds__(NTHR) void k_l1(const int* __restrict__ esrc, const int* __restrict__ edst,
                                             const int* __restrict__ erel, const float* __restrict__ enorm,
                                             const float* __restrict__ h0, const float* __restrict__ Wr1,
                                             float* __restrict__ h1) {
    __shared__ float w[N_RELS * 260];  // stride 260 floats: 16B-aligned rows, breaks 1024B bank stride
    for (int i = threadIdx.x; i < N_RELS * 256; i += NTHR) {
        int r = i >> 8, rest = i & 255;
        w[r * 260 + rest] = Wr1[i];
    }
    __syncthreads();
    for (int e = blockIdx.x * NTHR + threadIdx.x; e < E_TOTAL; e += NBLK * NTHR) {
        int s = esrc[e], d = edst[e], r = erel[e];
        float nm = enorm[e];
        const float4* hp = reinterpret_cast<const float4*>(h0 + (size_t)s * HD);
        float4 hv0 = hp[0], hv1 = hp[1], hv2 = hp[2], hv3 = hp[3];
        float hs[16] = {fmaxf(hv0.x, 0.f), fmaxf(hv0.y, 0.f), fmaxf(hv0.z, 0.f), fmaxf(hv0.w, 0.f),
                        fmaxf(hv1.x, 0.f), fmaxf(hv1.y, 0.f), fmaxf(hv1.z, 0.f), fmaxf(hv1.w, 0.f),
                        fmaxf(hv2.x, 0.f), fmaxf(hv2.y, 0.f), fmaxf(hv2.z, 0.f), fmaxf(hv2.w, 0.f),
                        fmaxf(hv3.x, 0.f), fmaxf(hv3.y, 0.f), fmaxf(hv3.z, 0.f), fmaxf(hv3.w, 0.f)};
        float acc[16];
        #pragma unroll
        for (int h = 0; h < 16; ++h) acc[h] = 0.f;
        const float* wr = w + r * 260;
        #pragma unroll
        for (int i = 0; i < 16; ++i) {
            float hi = hs[i];
            const float4* wp = reinterpret_cast<const float4*>(wr + i * 16);
            fma4(acc + 0, hi, wp[0]);
            fma4(acc + 4, hi, wp[1]);
            fma4(acc + 8, hi, wp[2]);
            fma4(acc + 12, hi, wp[3]);
        }
        float* out = h1 + (size_t)d * HD;
        #pragma unroll
        for (int h = 0; h < 16; ++h) atomicAdd(out + h, nm * acc[h]);
    }
}

// Layer 2: h2[dst] += norm * (relu(h1[src]) @ Wr2[rel])   (16 -> 8)
__global__ __launch_bounds__(NTHR) void k_l2(const int* __restrict__ esrc, const int* __restrict__ edst,
                                             const int* __restrict__ erel, const float* __restrict__ enorm,
                                             const float* __restrict__ h1, const float* __restrict__ Wr2,
                                             float* __restrict__ h2) {
    __shared__ float w[N_RELS * 132];  // 128 + 4 pad; rows 16B-aligned
    for (int i = threadIdx.x; i < N_RELS * 128; i += NTHR) {
        int r = i >> 7, rest = i & 127;
        w[r * 132 + rest] = Wr2[i];
    }
    __syncthreads();
    for (int e = blockIdx.x * NTHR + threadIdx.x; e < E_TOTAL; e += NBLK * NTHR) {
        int s = esrc[e], d = edst[e], r = erel[e];
        float nm = enorm[e];
        const float4* hp = reinterpret_cast<const float4*>(h1 + (size_t)s * HD);
        float4 hv0 = hp[0], hv1 = hp[1], hv2 = hp[2], hv3 = hp[3];
        float hs[16] = {fmaxf(hv0.x, 0.f), fmaxf(hv0.y, 0.f), fmaxf(hv0.z, 0.f), fmaxf(hv0.w, 0.f),
                        fmaxf(hv1.x, 0.f), fmaxf(hv1.y, 0.f), fmaxf(hv1.z, 0.f), fmaxf(hv1.w, 0.f),
                        fmaxf(hv2.x, 0.f), fmaxf(hv2.y, 0.f), fmaxf(hv2.z, 0.f), fmaxf(hv2.w, 0.f),
                        fmaxf(hv3.x, 0.f), fmaxf(hv3.y, 0.f), fmaxf(hv3.z, 0.f), fmaxf(hv3.w, 0.f)};
        float acc[8];
        #pragma unroll
        for (int h = 0; h < 8; ++h) acc[h] = 0.f;
        const float* wr = w + r * 132;
        #pragma unroll
        for (int i = 0; i < 16; ++i) {
            float hi = hs[i];
            const float4* wp = reinterpret_cast<const float4*>(wr + i * 8);
            fma4(acc + 0, hi, wp[0]);
            fma4(acc + 4, hi, wp[1]);
        }
        float* out = h2 + (size_t)d * OD;
        #pragma unroll
        for (int h = 0; h < 8; ++h) atomicAdd(out + h, nm * acc[h]);
    }
}

__global__ __launch_bounds__(NTHR) void k_softmax(const float* __restrict__ h2, float* __restrict__ out) {
    int n = blockIdx.x * NTHR + threadIdx.x;
    if (n >= N_NODES) return;
    const float4* p = reinterpret_cast<const float4*>(h2 + (size_t)n * OD);
    float4 a = p[0], b = p[1];
    float v[8] = {a.x, a.y, a.z, a.w, b.x, b.y, b.z, b.w};
    float m = v[0];
    #pragma unroll
    for (int i = 1; i < 8; ++i) m = fmaxf(m, v[i]);
    float ssum = 0.f;
    #pragma unroll
    for (int i = 0; i < 8; ++i) { v[i] = __expf(v[i] - m); ssum += v[i]; }
    float inv = 1.0f / ssum;
    float4 o0 = make_float4(v[0] * inv, v[1] * inv, v[2] * inv, v[3] * inv);
    float4 o1 = make_float4(v[4] * inv, v[5] * inv, v[6] * inv, v[7] * inv);
    float4* q = reinterpret_cast<float4*>(out + (size_t)n * OD);
    q[0] = o0;
    q[1] = o1;
}

extern "C" void kernel_launch(void* const* d_in, const int* in_sizes, int n_in,
                              void* d_out, int out_size, void* d_ws, size_t ws_size,
                              hipStream_t stream) {
    const int* esrc = (const int*)d_in[0];
    const int* edst = (const int*)d_in[1];
    const int* erel = (const int*)d_in[2];
    const float* enorm = (const float*)d_in[3];
    const float* W0 = (const float*)d_in[4];
    const float* C0 = (const float*)d_in[5];
    const float* W1 = (const float*)d_in[6];
    const float* C1 = (const float*)d_in[7];
    const float* W2 = (const float*)d_in[8];
    const float* C2 = (const float*)d_in[9];

    float* ws = (float*)d_ws;
    float* h0  = ws;                 // 1,600,000 floats
    float* h1  = ws + 1600000;       // 1,600,000
    float* h2  = ws + 3200000;       //   800,000
    float* Wr1 = ws + 4000000;       //    12,800
    float* Wr2 = ws + 4012800;       //     6,400

    // zero the accumulators (h0,h1,h2 contiguous)
    hipMemsetAsync(h0, 0, (size_t)4000000 * sizeof(float), stream);

    k_wr<<<(N_RELS * 256 + N_RELS * 128 + NTHR - 1) / NTHR, NTHR, 0, stream>>>(W1, C1, W2, C2, Wr1, Wr2);
    k_l0<<<NBLK, NTHR, 0, stream>>>(esrc, edst, erel, enorm, W0, C0, h0);
    k_l1<<<NBLK, NTHR, 0, stream>>>(esrc, edst, erel, enorm, h0, Wr1, h1);
    k_l2<<<NBLK, NTHR, 0, stream>>>(esrc, edst, erel, enorm, h1, Wr2, h2);
    k_softmax<<<(N_NODES + NTHR - 1) / NTHR, NTHR, 0, stream>>>(h2, (float*)d_out);
}

// Round 2
// 1025.584 us; speedup vs baseline: 6.7552x; 6.7552x over previous
//
#include <hip/hip_runtime.h>
#include <cstddef>
#include <cstdint>

#define E_TOTAL 3200000
#define N_NODES 100000
#define N_RELS 50
#define N_BASES 16
#define HD 16
#define OD 8
#define NTHR 256

typedef unsigned int u32;

__device__ __forceinline__ float bl16(u32 u) { return __uint_as_float(u << 16); }
__device__ __forceinline__ float bh16(u32 u) { return __uint_as_float(u & 0xffff0000u); }

// ---------------- shared: basis-combined dense weights ----------------
// Wr1[r,i,o] = sum_b C1[r,b]*W1[b,i,o]  (50x16x16); Wr2: 50x16x8
__global__ __launch_bounds__(NTHR) void k_wr(const float* __restrict__ W1, const float* __restrict__ C1,
                                             const float* __restrict__ W2, const float* __restrict__ C2,
                                             float* __restrict__ Wr1, float* __restrict__ Wr2) {
    int idx = blockIdx.x * NTHR + threadIdx.x;
    const int n1 = N_RELS * 256;
    if (idx < n1) {
        int r = idx >> 8, io = idx & 255;
        float acc = 0.f;
        #pragma unroll
        for (int b = 0; b < N_BASES; ++b)
            acc = fmaf(C1[r * N_BASES + b], W1[b * 256 + io], acc);
        Wr1[idx] = acc;
    } else if (idx < n1 + N_RELS * 128) {
        int j = idx - n1;
        int r = j >> 7, io = j & 127;
        float acc = 0.f;
        #pragma unroll
        for (int b = 0; b < N_BASES; ++b)
            acc = fmaf(C2[r * N_BASES + b], W2[b * 128 + io], acc);
        Wr2[j] = acc;
    }
}

// ======================= TIER A (sorted, ~92 MB ws) =======================

// W0[b][n][h] fp32 -> W0t[n][h][b] bf16 (32 B per (n,h), 512 B per node)
__global__ __launch_bounds__(NTHR) void k_transpose(const float* __restrict__ W0, uint4* __restrict__ W0t) {
    int t = blockIdx.x * NTHR + threadIdx.x;  // n*16+h
    if (t >= N_NODES * HD) return;
    u32 u[8];
    #pragma unroll
    for (int k = 0; k < 8; ++k) {
        u32 a = __float_as_uint(W0[(size_t)(2 * k) * (N_NODES * HD) + t]);
        u32 b = __float_as_uint(W0[(size_t)(2 * k + 1) * (N_NODES * HD) + t]);
        a = (a + 0x7fffu + ((a >> 16) & 1u)) >> 16;  // RNE to bf16
        b = (b + 0x7fffu + ((b >> 16) & 1u)) >> 16;
        u[k] = a | (b << 16);
    }
    W0t[t * 2] = make_uint4(u[0], u[1], u[2], u[3]);
    W0t[t * 2 + 1] = make_uint4(u[4], u[5], u[6], u[7]);
}

__global__ __launch_bounds__(NTHR) void k_hist(const int* __restrict__ edst, int* __restrict__ cnt) {
    int e = blockIdx.x * NTHR + threadIdx.x;
    if (e < E_TOTAL) atomicAdd(&cnt[edst[e]], 1);
}

__global__ __launch_bounds__(NTHR) void k_scan1(const int* __restrict__ cnt, int* __restrict__ excl,
                                                int* __restrict__ bsum) {
    __shared__ int s[NTHR];
    int i = blockIdx.x * NTHR + threadIdx.x;
    int v = (i < N_NODES) ? cnt[i] : 0;
    s[threadIdx.x] = v;
    __syncthreads();
    #pragma unroll
    for (int off = 1; off < NTHR; off <<= 1) {
        int t = (threadIdx.x >= off) ? s[threadIdx.x - off] : 0;
        __syncthreads();
        s[threadIdx.x] += t;
        __syncthreads();
    }
    if (i < N_NODES) excl[i] = s[threadIdx.x] - v;
    if (threadIdx.x == NTHR - 1) bsum[blockIdx.x] = s[NTHR - 1];
}

__global__ void k_scan2(int* __restrict__ bsum, int nb) {
    __shared__ int s[512];
    int tid = threadIdx.x;
    int v = (tid < nb) ? bsum[tid] : 0;
    s[tid] = v;
    __syncthreads();
    for (int off = 1; off < 512; off <<= 1) {
        int t = (tid >= off) ? s[tid - off] : 0;
        __syncthreads();
        s[tid] += t;
        __syncthreads();
    }
    if (tid < nb) bsum[tid] = s[tid] - v;
}

__global__ __launch_bounds__(NTHR) void k_scan3(const int* __restrict__ excl, const int* __restrict__ bsum,
                                                int* __restrict__ row_ptr, int* __restrict__ head) {
    int i = blockIdx.x * NTHR + threadIdx.x;
    if (i < N_NODES) {
        int v = excl[i] + bsum[blockIdx.x];
        row_ptr[i] = v;
        head[i] = v;
    }
    if (i == 0) row_ptr[N_NODES] = E_TOTAL;
}

__global__ __launch_bounds__(NTHR) void k_scatter(const int* __restrict__ esrc, const int* __restrict__ edst,
                                                  const int* __restrict__ erel, const float* __restrict__ enorm,
                                                  int* __restrict__ head, uint2* __restrict__ rec) {
    int e = blockIdx.x * NTHR + threadIdx.x;
    if (e >= E_TOTAL) return;
    int d = edst[e];
    int pos = atomicAdd(&head[d], 1);
    u32 sr = (u32)esrc[e] | ((u32)erel[e] << 17);  // src<2^17, rel<50
    rec[pos] = make_uint2(sr, __float_as_uint(enorm[e]));
}

// L0: wave per dst; 4 edge-groups x 16 dims. h0[d,h] = relu(sum_e nm * dot16(C0[r], W0t[s,h,:]))
__global__ __launch_bounds__(NTHR) void k_l0s(const uint2* __restrict__ rec, const int* __restrict__ row_ptr,
                                              const float* __restrict__ C0, const uint4* __restrict__ W0t,
                                              float* __restrict__ h0) {
    int lane = threadIdx.x & 63;
    int g = lane >> 4, h = lane & 15;
    int wave = (blockIdx.x * NTHR + threadIdx.x) >> 6;
    int nw = (gridDim.x * NTHR) >> 6;
    for (int d = wave; d < N_NODES; d += nw) {
        int s0 = row_ptr[d], s1 = row_ptr[d + 1];
        float acc = 0.f;
        for (int j = s0 + g; j < s1; j += 4) {
            uint2 rc = rec[j];
            int src = rc.x & 0x1FFFF;
            int rel = rc.x >> 17;
            float nm = __uint_as_float(rc.y);
            const float4* cp = (const float4*)(C0 + rel * 16);
            float4 c0 = __ldg(cp), c1 = __ldg(cp + 1), c2 = __ldg(cp + 2), c3 = __ldg(cp + 3);
            uint4 q0 = W0t[src * 32 + h * 2];
            uint4 q1 = W0t[src * 32 + h * 2 + 1];
            float m = bl16(q0.x) * c0.x + bh16(q0.x) * c0.y + bl16(q0.y) * c0.z + bh16(q0.y) * c0.w +
                      bl16(q0.z) * c1.x + bh16(q0.z) * c1.y + bl16(q0.w) * c1.z + bh16(q0.w) * c1.w +
                      bl16(q1.x) * c2.x + bh16(q1.x) * c2.y + bl16(q1.y) * c2.z + bh16(q1.y) * c2.w +
                      bl16(q1.z) * c3.x + bh16(q1.z) * c3.y + bl16(q1.w) * c3.z + bh16(q1.w) * c3.w;
            acc = fmaf(nm, m, acc);
        }
        acc += __shfl_xor(acc, 16);
        acc += __shfl_xor(acc, 32);
        if (lane < 16) h0[(size_t)d * HD + lane] = fmaxf(acc, 0.f);  // fused relu
    }
}

// L1: wave per dst; 4 edge-groups x 16 dims; Wr1 in LDS as [r][h][i], h-stride 20 (bank-tiled), r-stride 324
__global__ __launch_bounds__(NTHR) void k_l1s(const uint2* __restrict__ rec, const int* __restrict__ row_ptr,
                                              const float* __restrict__ Wr1, const float* __restrict__ h0,
                                              float* __restrict__ h1) {
    __shared__ float w[N_RELS * 324];  // 64.8 KB
    for (int idx = threadIdx.x; idx < N_RELS * 256; idx += NTHR) {
        int r = idx >> 8, rem = idx & 255, i = rem >> 4, hh = rem & 15;
        w[r * 324 + hh * 20 + i] = Wr1[idx];
    }
    __syncthreads();
    int lane = threadIdx.x & 63;
    int g = lane >> 4, h = lane & 15;
    int wave = (blockIdx.x * NTHR + threadIdx.x) >> 6;
    int nw = (gridDim.x * NTHR) >> 6;
    const float* wh = w + h * 20;
    for (int d = wave; d < N_NODES; d += nw) {
        int s0 = row_ptr[d], s1 = row_ptr[d + 1];
        float acc = 0.f;
        for (int j = s0 + g; j < s1; j += 4) {
            uint2 rc = rec[j];
            int src = rc.x & 0x1FFFF;
            int rel = rc.x >> 17;
            float nm = __uint_as_float(rc.y);
            const float4* hp = (const float4*)(h0 + (size_t)src * HD);
            float4 a0 = __ldg(hp), a1 = __ldg(hp + 1), a2 = __ldg(hp + 2), a3 = __ldg(hp + 3);
            const float4* wp = (const float4*)(wh + rel * 324);
            float4 w0 = wp[0], w1 = wp[1], w2 = wp[2], w3 = wp[3];
            float m = a0.x * w0.x + a0.y * w0.y + a0.z * w0.z + a0.w * w0.w +
                      a1.x * w1.x + a1.y * w1.y + a1.z * w1.z + a1.w * w1.w +
                      a2.x * w2.x + a2.y * w2.y + a2.z * w2.z + a2.w * w2.w +
                      a3.x * w3.x + a3.y * w3.y + a3.z * w3.z + a3.w * w3.w;
            acc = fmaf(nm, m, acc);
        }
        acc += __shfl_xor(acc, 16);
        acc += __shfl_xor(acc, 32);
        if (lane < 16) h1[(size_t)d * HD + lane] = fmaxf(acc, 0.f);  // fused relu
    }
}

// L2 + softmax: wave per dst; 8 edge-groups x 8 dims; Wr2 in LDS [r][o][i], o-stride 20, r-stride 164
__global__ __launch_bounds__(NTHR) void k_l2s(const uint2* __restrict__ rec, const int* __restrict__ row_ptr,
                                              const float* __restrict__ Wr2, const float* __restrict__ h1,
                                              float* __restrict__ out) {
    __shared__ float w[N_RELS * 164];  // 32.8 KB
    for (int idx = threadIdx.x; idx < N_RELS * 128; idx += NTHR) {
        int r = idx >> 7, rem = idx & 127, i = rem >> 3, o = rem & 7;
        w[r * 164 + o * 20 + i] = Wr2[idx];
    }
    __syncthreads();
    int lane = threadIdx.x & 63;
    int g = lane >> 3, o = lane & 7;
    int wave = (blockIdx.x * NTHR + threadIdx.x) >> 6;
    int nw = (gridDim.x * NTHR) >> 6;
    const float* wo = w + o * 20;
    for (int d = wave; d < N_NODES; d += nw) {
        int s0 = row_ptr[d], s1 = row_ptr[d + 1];
        float acc = 0.f;
        for (int j = s0 + g; j < s1; j += 8) {
            uint2 rc = rec[j];
            int src = rc.x & 0x1FFFF;
            int rel = rc.x >> 17;
            float nm = __uint_as_float(rc.y);
            const float4* hp = (const float4*)(h1 + (size_t)src * HD);
            float4 a0 = __ldg(hp), a1 = __ldg(hp + 1), a2 = __ldg(hp + 2), a3 = __ldg(hp + 3);
            const float4* wp = (const float4*)(wo + rel * 164);
            float4 w0 = wp[0], w1 = wp[1], w2 = wp[2], w3 = wp[3];
            float m = a0.x * w0.x + a0.y * w0.y + a0.z * w0.z + a0.w * w0.w +
                      a1.x * w1.x + a1.y * w1.y + a1.z * w1.z + a1.w * w1.w +
                      a2.x * w2.x + a2.y * w2.y + a2.z * w2.z + a2.w * w2.w +
                      a3.x * w3.x + a3.y * w3.y + a3.z * w3.z + a3.w * w3.w;
            acc = fmaf(nm, m, acc);
        }
        acc += __shfl_xor(acc, 8);
        acc += __shfl_xor(acc, 16);
        acc += __shfl_xor(acc, 32);
        // fused softmax across the 8 output dims (lanes within 8-lane block)
        float mx = acc;
        mx = fmaxf(mx, __shfl_xor(mx, 1));
        mx = fmaxf(mx, __shfl_xor(mx, 2));
        mx = fmaxf(mx, __shfl_xor(mx, 4));
        float ex = __expf(acc - mx);
        float sm = ex;
        sm += __shfl_xor(sm, 1);
        sm += __shfl_xor(sm, 2);
        sm += __shfl_xor(sm, 4);
        if (lane < 8) out[(size_t)d * OD + o] = ex / sm;
    }
}

// ======================= TIER B (fallback, 16.1 MB ws; round-1 code) =======================
#define NBLK 2560

__device__ __forceinline__ void fma4(float* acc, float c, float4 w) {
    acc[0] = fmaf(c, w.x, acc[0]);
    acc[1] = fmaf(c, w.y, acc[1]);
    acc[2] = fmaf(c, w.z, acc[2]);
    acc[3] = fmaf(c, w.w, acc[3]);
}

__global__ __launch_bounds__(NTHR) void k_l0_old(const int* __restrict__ esrc, const int* __restrict__ edst,
                                                 const int* __restrict__ erel, const float* __restrict__ enorm,
                                                 const float* __restrict__ W0, const float* __restrict__ C0,
                                                 float* __restrict__ h0) {
    for (int e = blockIdx.x * NTHR + threadIdx.x; e < E_TOTAL; e += NBLK * NTHR) {
        int s = esrc[e], d = edst[e], r = erel[e];
        float nm = enorm[e];
        const float4* cp = reinterpret_cast<const float4*>(C0 + r * N_BASES);
        float4 c0 = cp[0], c1 = cp[1], c2 = cp[2], c3 = cp[3];
        float coef[16] = {c0.x, c0.y, c0.z, c0.w, c1.x, c1.y, c1.z, c1.w,
                          c2.x, c2.y, c2.z, c2.w, c3.x, c3.y, c3.z, c3.w};
        float acc[16];
        #pragma unroll
        for (int h = 0; h < 16; ++h) acc[h] = 0.f;
        const float* wbase = W0 + (size_t)s * HD;
        #pragma unroll
        for (int b = 0; b < N_BASES; ++b) {
            const float4* wp = reinterpret_cast<const float4*>(wbase + (size_t)b * (N_NODES * HD));
            float cb = coef[b];
            fma4(acc + 0, cb, wp[0]);
            fma4(acc + 4, cb, wp[1]);
            fma4(acc + 8, cb, wp[2]);
            fma4(acc + 12, cb, wp[3]);
        }
        float* outp = h0 + (size_t)d * HD;
        #pragma unroll
        for (int h = 0; h < 16; ++h) atomicAdd(outp + h, nm * acc[h]);
    }
}

__global__ __launch_bounds__(NTHR) void k_l1_old(const int* __restrict__ esrc, const int* __restrict__ edst,
                                                 const int* __restrict__ erel, const float* __restrict__ enorm,
                                                 const float* __restrict__ h0, const float* __restrict__ Wr1,
                                                 float* __restrict__ h1) {
    __shared__ float w[N_RELS * 260];
    for (int i = threadIdx.x; i < N_RELS * 256; i += NTHR) {
        int r = i >> 8, rest = i & 255;
        w[r * 260 + rest] = Wr1[i];
    }
    __syncthreads();
    for (int e = blockIdx.x * NTHR + threadIdx.x; e < E_TOTAL; e += NBLK * NTHR) {
        int s = esrc[e], d = edst[e], r = erel[e];
        float nm = enorm[e];
        const float4* hp = reinterpret_cast<const float4*>(h0 + (size_t)s * HD);
        float4 hv0 = hp[0], hv1 = hp[1], hv2 = hp[2], hv3 = hp[3];
        float hs[16] = {fmaxf(hv0.x, 0.f), fmaxf(hv0.y, 0.f), fmaxf(hv0.z, 0.f), fmaxf(hv0.w, 0.f),
                        fmaxf(hv1.x, 0.f), fmaxf(hv1.y, 0.f), fmaxf(hv1.z, 0.f), fmaxf(hv1.w, 0.f),
                        fmaxf(hv2.x, 0.f), fmaxf(hv2.y, 0.f), fmaxf(hv2.z, 0.f), fmaxf(hv2.w, 0.f),
                        fmaxf(hv3.x, 0.f), fmaxf(hv3.y, 0.f), fmaxf(hv3.z, 0.f), fmaxf(hv3.w, 0.f)};
        float acc[16];
        #pragma unroll
        for (int h = 0; h < 16; ++h) acc[h] = 0.f;
        const float* wr = w + r * 260;
        #pragma unroll
        for (int i = 0; i < 16; ++i) {
            float hi = hs[i];
            const float4* wp = reinterpret_cast<const float4*>(wr + i * 16);
            fma4(acc + 0, hi, wp[0]);
            fma4(acc + 4, hi, wp[1]);
            fma4(acc + 8, hi, wp[2]);
            fma4(acc + 12, hi, wp[3]);
        }
        float* outp = h1 + (size_t)d * HD;
        #pragma unroll
        for (int h = 0; h < 16; ++h) atomicAdd(outp + h, nm * acc[h]);
    }
}

__global__ __launch_bounds__(NTHR) void k_l2_old(const int* __restrict__ esrc, const int* __restrict__ edst,
                                                 const int* __restrict__ erel, const float* __restrict__ enorm,
                                                 const float* __restrict__ h1, const float* __restrict__ Wr2,
                                                 float* __restrict__ h2) {
    __shared__ float w[N_RELS * 132];
    for (int i = threadIdx.x; i < N_RELS * 128; i += NTHR) {
        int r = i >> 7, rest = i & 127;
        w[r * 132 + rest] = Wr2[i];
    }
    __syncthreads();
    for (int e = blockIdx.x * NTHR + threadIdx.x; e < E_TOTAL; e += NBLK * NTHR) {
        int s = esrc[e], d = edst[e], r = erel[e];
        float nm = enorm[e];
        const float4* hp = reinterpret_cast<const float4*>(h1 + (size_t)s * HD);
        float4 hv0 = hp[0], hv1 = hp[1], hv2 = hp[2], hv3 = hp[3];
        float hs[16] = {fmaxf(hv0.x, 0.f), fmaxf(hv0.y, 0.f), fmaxf(hv0.z, 0.f), fmaxf(hv0.w, 0.f),
                        fmaxf(hv1.x, 0.f), fmaxf(hv1.y, 0.f), fmaxf(hv1.z, 0.f), fmaxf(hv1.w, 0.f),
                        fmaxf(hv2.x, 0.f), fmaxf(hv2.y, 0.f), fmaxf(hv2.z, 0.f), fmaxf(hv2.w, 0.f),
                        fmaxf(hv3.x, 0.f), fmaxf(hv3.y, 0.f), fmaxf(hv3.z, 0.f), fmaxf(hv3.w, 0.f)};
        float acc[8];
        #pragma unroll
        for (int h = 0; h < 8; ++h) acc[h] = 0.f;
        const float* wr = w + r * 132;
        #pragma unroll
        for (int i = 0; i < 16; ++i) {
            float hi = hs[i];
            const float4* wp = reinterpret_cast<const float4*>(wr + i * 8);
            fma4(acc + 0, hi, wp[0]);
            fma4(acc + 4, hi, wp[1]);
        }
        float* outp = h2 + (size_t)d * OD;
        #pragma unroll
        for (int h = 0; h < 8; ++h) atomicAdd(outp + h, nm * acc[h]);
    }
}

__global__ __launch_bounds__(NTHR) void k_softmax(const float* __restrict__ h2, float* __restrict__ out) {
    int n = blockIdx.x * NTHR + threadIdx.x;
    if (n >= N_NODES) return;
    const float4* p = reinterpret_cast<const float4*>(h2 + (size_t)n * OD);
    float4 a = p[0], b = p[1];
    float v[8] = {a.x, a.y, a.z, a.w, b.x, b.y, b.z, b.w};
    float m = v[0];
    #pragma unroll
    for (int i = 1; i < 8; ++i) m = fmaxf(m, v[i]);
    float ssum = 0.f;
    #pragma unroll
    for (int i = 0; i < 8; ++i) {
        v[i] = __expf(v[i] - m);
        ssum += v[i];
    }
    float inv = 1.0f / ssum;
    float4 o0 = make_float4(v[0] * inv, v[1] * inv, v[2] * inv, v[3] * inv);
    float4 o1 = make_float4(v[4] * inv, v[5] * inv, v[6] * inv, v[7] * inv);
    float4* q = reinterpret_cast<float4*>(out + (size_t)n * OD);
    q[0] = o0;
    q[1] = o1;
}

// =========================================================================

extern "C" void kernel_launch(void* const* d_in, const int* in_sizes, int n_in,
                              void* d_out, int out_size, void* d_ws, size_t ws_size,
                              hipStream_t stream) {
    const int* esrc = (const int*)d_in[0];
    const int* edst = (const int*)d_in[1];
    const int* erel = (const int*)d_in[2];
    const float* enorm = (const float*)d_in[3];
    const float* W0 = (const float*)d_in[4];
    const float* C0 = (const float*)d_in[5];
    const float* W1 = (const float*)d_in[6];
    const float* C1 = (const float*)d_in[7];
    const float* W2 = (const float*)d_in[8];
    const float* C2 = (const float*)d_in[9];

    if (ws_size >= (size_t)92000000) {
        // ---- Tier A: sorted CSR + bf16 node-major W0 ----
        char* wsb = (char*)d_ws;
        uint4* W0t = (uint4*)wsb;                       // 51,200,000 B
        uint2* rec = (uint2*)(wsb + 51200000);          // 25,600,000 B
        float* h0 = (float*)(wsb + 76800000);           //  6,400,000 B
        float* h1 = (float*)(wsb + 83200000);           //  6,400,000 B
        float* Wr1 = (float*)(wsb + 89600000);          //     51,200 B
        float* Wr2 = (float*)(wsb + 89651200);          //     25,600 B
        int* cnt = (int*)(wsb + 89676800);              //    400,000 B
        int* bsum = (int*)(wsb + 90076800);             //      2,048 B
        int* excl = (int*)(wsb + 90078848);             //    400,000 B
        int* row_ptr = (int*)(wsb + 90478848);          //    400,004 B
        int* head = (int*)(wsb + 90878852);             //    400,000 B

        hipMemsetAsync(cnt, 0, N_NODES * sizeof(int), stream);

        k_transpose<<<(N_NODES * HD) / NTHR, NTHR, 0, stream>>>(W0, W0t);
        k_hist<<<E_TOTAL / NTHR, NTHR, 0, stream>>>(edst, cnt);
        int nsb = (N_NODES + NTHR - 1) / NTHR;  // 391
        k_scan1<<<nsb, NTHR, 0, stream>>>(cnt, excl, bsum);
        k_scan2<<<1, 512, 0, stream>>>(bsum, nsb);
        k_scan3<<<nsb, NTHR, 0, stream>>>(excl, bsum, row_ptr, head);
        k_scatter<<<E_TOTAL / NTHR, NTHR, 0, stream>>>(esrc, edst, erel, enorm, head, rec);
        k_wr<<<(N_RELS * 256 + N_RELS * 128 + NTHR - 1) / NTHR, NTHR, 0, stream>>>(W1, C1, W2, C2, Wr1, Wr2);

        k_l0s<<<12500, NTHR, 0, stream>>>(rec, row_ptr, C0, W0t, h0);
        k_l1s<<<4096, NTHR, 0, stream>>>(rec, row_ptr, Wr1, h0, h1);
        k_l2s<<<4096, NTHR, 0, stream>>>(rec, row_ptr, Wr2, h1, (float*)d_out);
    } else {
        // ---- Tier B: round-1 fallback (atomics) ----
        float* ws = (float*)d_ws;
        float* h0 = ws;
        float* h1 = ws + 1600000;
        float* h2 = ws + 3200000;
        float* Wr1 = ws + 4000000;
        float* Wr2 = ws + 4012800;

        hipMemsetAsync(h0, 0, (size_t)4000000 * sizeof(float), stream);

        k_wr<<<(N_RELS * 256 + N_RELS * 128 + NTHR - 1) / NTHR, NTHR, 0, stream>>>(W1, C1, W2, C2, Wr1, Wr2);
        k_l0_old<<<NBLK, NTHR, 0, stream>>>(esrc, edst, erel, enorm, W0, C0, h0);
        k_l1_old<<<NBLK, NTHR, 0, stream>>>(esrc, edst, erel, enorm, h0, Wr1, h1);
        k_l2_old<<<NBLK, NTHR, 0, stream>>>(esrc, edst, erel, enorm, h1, Wr2, h2);
        k_softmax<<<(N_NODES + NTHR - 1) / NTHR, NTHR, 0, stream>>>(h2, (float*)d_out);
    }
}

// Round 3
// 705.563 us; speedup vs baseline: 9.8191x; 1.4536x over previous
//
#include <hip/hip_runtime.h>
#include <cstddef>
#include <cstdint>

#define E_TOTAL 3200000
#define N_NODES 100000
#define N_RELS 50
#define N_BASES 16
#define HD 16
#define OD 8
#define NTHR 256

typedef unsigned int u32;

__device__ __forceinline__ float bl16(u32 u) { return __uint_as_float(u << 16); }
__device__ __forceinline__ float bh16(u32 u) { return __uint_as_float(u & 0xffff0000u); }
__device__ __forceinline__ u32 packbf(float x0, float x1) {
    u32 a = __float_as_uint(x0), b = __float_as_uint(x1);
    a = (a + 0x7fffu + ((a >> 16) & 1u)) >> 16;
    b = (b + 0x7fffu + ((b >> 16) & 1u)) >> 16;
    return a | (b << 16);
}

// ---------------- basis-combined dense weights (fp32, in ws) ----------------
__global__ __launch_bounds__(NTHR) void k_wr(const float* __restrict__ W1, const float* __restrict__ C1,
                                             const float* __restrict__ W2, const float* __restrict__ C2,
                                             float* __restrict__ Wr1, float* __restrict__ Wr2) {
    int idx = blockIdx.x * NTHR + threadIdx.x;
    const int n1 = N_RELS * 256;
    if (idx < n1) {
        int r = idx >> 8, io = idx & 255;
        float acc = 0.f;
        #pragma unroll
        for (int b = 0; b < N_BASES; ++b)
            acc = fmaf(C1[r * N_BASES + b], W1[b * 256 + io], acc);
        Wr1[idx] = acc;
    } else if (idx < n1 + N_RELS * 128) {
        int j = idx - n1;
        int r = j >> 7, io = j & 127;
        float acc = 0.f;
        #pragma unroll
        for (int b = 0; b < N_BASES; ++b)
            acc = fmaf(C2[r * N_BASES + b], W2[b * 128 + io], acc);
        Wr2[j] = acc;
    }
}

// ---------------- sort pipeline (dst-sorted CSR of packed edge records) ----------------
__global__ __launch_bounds__(NTHR) void k_hist(const int* __restrict__ edst, int* __restrict__ cnt) {
    int e = blockIdx.x * NTHR + threadIdx.x;
    if (e < E_TOTAL) atomicAdd(&cnt[edst[e]], 1);
}

__global__ __launch_bounds__(NTHR) void k_scan1(const int* __restrict__ cnt, int* __restrict__ excl,
                                                int* __restrict__ bsum) {
    __shared__ int s[NTHR];
    int i = blockIdx.x * NTHR + threadIdx.x;
    int v = (i < N_NODES) ? cnt[i] : 0;
    s[threadIdx.x] = v;
    __syncthreads();
    #pragma unroll
    for (int off = 1; off < NTHR; off <<= 1) {
        int t = (threadIdx.x >= off) ? s[threadIdx.x - off] : 0;
        __syncthreads();
        s[threadIdx.x] += t;
        __syncthreads();
    }
    if (i < N_NODES) excl[i] = s[threadIdx.x] - v;
    if (threadIdx.x == NTHR - 1) bsum[blockIdx.x] = s[NTHR - 1];
}

__global__ void k_scan2(int* __restrict__ bsum, int nb) {
    __shared__ int s[512];
    int tid = threadIdx.x;
    int v = (tid < nb) ? bsum[tid] : 0;
    s[tid] = v;
    __syncthreads();
    for (int off = 1; off < 512; off <<= 1) {
        int t = (tid >= off) ? s[tid - off] : 0;
        __syncthreads();
        s[tid] += t;
        __syncthreads();
    }
    if (tid < nb) bsum[tid] = s[tid] - v;
}

__global__ __launch_bounds__(NTHR) void k_scan3(const int* __restrict__ excl, const int* __restrict__ bsum,
                                                int* __restrict__ row_ptr, int* __restrict__ head) {
    int i = blockIdx.x * NTHR + threadIdx.x;
    if (i < N_NODES) {
        int v = excl[i] + bsum[blockIdx.x];
        row_ptr[i] = v;
        head[i] = v;
    }
    if (i == 0) row_ptr[N_NODES] = E_TOTAL;
}

__global__ __launch_bounds__(NTHR) void k_scatter(const int* __restrict__ esrc, const int* __restrict__ edst,
                                                  const int* __restrict__ erel, const float* __restrict__ enorm,
                                                  int* __restrict__ head, uint2* __restrict__ rec) {
    int e = blockIdx.x * NTHR + threadIdx.x;
    if (e >= E_TOTAL) return;
    int d = edst[e];
    int pos = atomicAdd(&head[d], 1);
    u32 sr = (u32)esrc[e] | ((u32)erel[e] << 17);  // src<2^17, rel<50
    rec[pos] = make_uint2(sr, __float_as_uint(enorm[e]));
}

// ================= TIER A+ : dense L0 embedding =================

// emb0[r][n][h] = sum_b C0[r,b]*W0[b,n,h], bf16. Thread t=(n'*16+h): its 16 basis
// values are exactly its own 16 coalesced loads -> registers, no LDS transpose.
__global__ __launch_bounds__(NTHR) void k_emb0(const float* __restrict__ W0, const float* __restrict__ C0,
                                               ushort* __restrict__ emb) {
    int t = threadIdx.x;
    size_t base = (size_t)blockIdx.x * 256 + t;  // n*16+h, 6250 blocks exactly
    float w[16];
    #pragma unroll
    for (int b = 0; b < 16; ++b) w[b] = W0[(size_t)b * (N_NODES * HD) + base];
    __shared__ float c[N_RELS * 16];
    for (int i = t; i < N_RELS * 16; i += NTHR) c[i] = C0[i];
    __syncthreads();
    for (int r = 0; r < N_RELS; ++r) {
        const float* cr = c + r * 16;
        float v = 0.f;
        #pragma unroll
        for (int b = 0; b < 16; ++b) v = fmaf(cr[b], w[b], v);
        u32 x = __float_as_uint(v);
        x = (x + 0x7fffu + ((x >> 16) & 1u)) >> 16;
        emb[(size_t)r * (N_NODES * HD) + base] = (ushort)x;
    }
}

// gather-accumulate 16-dim bf16 table rows by (rel,src), relu-fused, fp32 out.
// 8 edge-groups x 8 lanes; lane l holds dims {2l,2l+1}.
__global__ __launch_bounds__(NTHR) void k_g16(const uint2* __restrict__ rec, const int* __restrict__ row_ptr,
                                              const ushort* __restrict__ tbl, float* __restrict__ out) {
    int lane = threadIdx.x & 63;
    int g = lane >> 3, l = lane & 7;
    int wave = (blockIdx.x * NTHR + threadIdx.x) >> 6;
    int nw = (gridDim.x * NTHR) >> 6;
    for (int d = wave; d < N_NODES; d += nw) {
        int s0 = row_ptr[d], s1 = row_ptr[d + 1];
        float a0 = 0.f, a1 = 0.f;
        for (int j = s0 + g; j < s1; j += 8) {
            uint2 rc = rec[j];
            int src = rc.x & 0x1FFFF;
            int rel = rc.x >> 17;
            float nm = __uint_as_float(rc.y);
            u32 q = *(const u32*)(tbl + ((size_t)rel * N_NODES + src) * HD + l * 2);
            a0 = fmaf(nm, bl16(q), a0);
            a1 = fmaf(nm, bh16(q), a1);
        }
        a0 += __shfl_xor(a0, 8);  a1 += __shfl_xor(a1, 8);
        a0 += __shfl_xor(a0, 16); a1 += __shfl_xor(a1, 16);
        a0 += __shfl_xor(a0, 32); a1 += __shfl_xor(a1, 32);
        if (lane < 8)
            *(float2*)(out + (size_t)d * HD + l * 2) = make_float2(fmaxf(a0, 0.f), fmaxf(a1, 0.f));
    }
}

// emb1[r][n][o] = sum_i h[n,i]*Wr1[r,i,o], bf16 out. One rel per block, 1KB LDS weight.
__global__ __launch_bounds__(NTHR) void k_emb1(const float* __restrict__ Wr1, const float* __restrict__ h,
                                               ushort* __restrict__ emb) {
    int r = blockIdx.x / 391, tile = blockIdx.x % 391;
    __shared__ float w[256];
    w[threadIdx.x] = Wr1[r * 256 + threadIdx.x];
    __syncthreads();
    int n = tile * NTHR + threadIdx.x;
    if (n >= N_NODES) return;
    const float4* hp = (const float4*)(h + (size_t)n * HD);
    float4 a0 = hp[0], a1 = hp[1], a2 = hp[2], a3 = hp[3];
    float hv[16] = {a0.x, a0.y, a0.z, a0.w, a1.x, a1.y, a1.z, a1.w,
                    a2.x, a2.y, a2.z, a2.w, a3.x, a3.y, a3.z, a3.w};
    float acc[16];
    #pragma unroll
    for (int o = 0; o < 16; ++o) acc[o] = 0.f;
    #pragma unroll
    for (int i = 0; i < 16; ++i) {
        const float4* wp = (const float4*)(w + i * 16);  // uniform addr -> LDS broadcast
        float4 w0 = wp[0], w1 = wp[1], w2 = wp[2], w3 = wp[3];
        float hi = hv[i];
        acc[0] = fmaf(hi, w0.x, acc[0]);  acc[1] = fmaf(hi, w0.y, acc[1]);
        acc[2] = fmaf(hi, w0.z, acc[2]);  acc[3] = fmaf(hi, w0.w, acc[3]);
        acc[4] = fmaf(hi, w1.x, acc[4]);  acc[5] = fmaf(hi, w1.y, acc[5]);
        acc[6] = fmaf(hi, w1.z, acc[6]);  acc[7] = fmaf(hi, w1.w, acc[7]);
        acc[8] = fmaf(hi, w2.x, acc[8]);  acc[9] = fmaf(hi, w2.y, acc[9]);
        acc[10] = fmaf(hi, w2.z, acc[10]); acc[11] = fmaf(hi, w2.w, acc[11]);
        acc[12] = fmaf(hi, w3.x, acc[12]); acc[13] = fmaf(hi, w3.y, acc[13]);
        acc[14] = fmaf(hi, w3.z, acc[14]); acc[15] = fmaf(hi, w3.w, acc[15]);
    }
    u32 p[8];
    #pragma unroll
    for (int k = 0; k < 8; ++k) p[k] = packbf(acc[2 * k], acc[2 * k + 1]);
    uint4* op = (uint4*)(emb + ((size_t)r * N_NODES + n) * HD);
    op[0] = make_uint4(p[0], p[1], p[2], p[3]);
    op[1] = make_uint4(p[4], p[5], p[6], p[7]);
}

// emb2[r][n][o] = sum_i h[n,i]*Wr2[r,i,o] (o<8), bf16 out.
__global__ __launch_bounds__(NTHR) void k_emb2(const float* __restrict__ Wr2, const float* __restrict__ h,
                                               ushort* __restrict__ emb) {
    int r = blockIdx.x / 391, tile = blockIdx.x % 391;
    __shared__ float w[128];
    if (threadIdx.x < 128) w[threadIdx.x] = Wr2[r * 128 + threadIdx.x];
    __syncthreads();
    int n = tile * NTHR + threadIdx.x;
    if (n >= N_NODES) return;
    const float4* hp = (const float4*)(h + (size_t)n * HD);
    float4 a0 = hp[0], a1 = hp[1], a2 = hp[2], a3 = hp[3];
    float hv[16] = {a0.x, a0.y, a0.z, a0.w, a1.x, a1.y, a1.z, a1.w,
                    a2.x, a2.y, a2.z, a2.w, a3.x, a3.y, a3.z, a3.w};
    float acc[8];
    #pragma unroll
    for (int o = 0; o < 8; ++o) acc[o] = 0.f;
    #pragma unroll
    for (int i = 0; i < 16; ++i) {
        const float4* wp = (const float4*)(w + i * 8);
        float4 w0 = wp[0], w1 = wp[1];
        float hi = hv[i];
        acc[0] = fmaf(hi, w0.x, acc[0]);  acc[1] = fmaf(hi, w0.y, acc[1]);
        acc[2] = fmaf(hi, w0.z, acc[2]);  acc[3] = fmaf(hi, w0.w, acc[3]);
        acc[4] = fmaf(hi, w1.x, acc[4]);  acc[5] = fmaf(hi, w1.y, acc[5]);
        acc[6] = fmaf(hi, w1.z, acc[6]);  acc[7] = fmaf(hi, w1.w, acc[7]);
    }
    u32 p[4];
    #pragma unroll
    for (int k = 0; k < 4; ++k) p[k] = packbf(acc[2 * k], acc[2 * k + 1]);
    *(uint4*)(emb + ((size_t)r * N_NODES + n) * OD) = make_uint4(p[0], p[1], p[2], p[3]);
}

// gather 8-dim bf16 rows + fused softmax. 16 edge-groups x 4 lanes.
__global__ __launch_bounds__(NTHR) void k_g8sm(const uint2* __restrict__ rec, const int* __restrict__ row_ptr,
                                               const ushort* __restrict__ tbl, float* __restrict__ out) {
    int lane = threadIdx.x & 63;
    int g = lane >> 2, l = lane & 3;
    int wave = (blockIdx.x * NTHR + threadIdx.x) >> 6;
    int nw = (gridDim.x * NTHR) >> 6;
    for (int d = wave; d < N_NODES; d += nw) {
        int s0 = row_ptr[d], s1 = row_ptr[d + 1];
        float a0 = 0.f, a1 = 0.f;
        for (int j = s0 + g; j < s1; j += 16) {
            uint2 rc = rec[j];
            int src = rc.x & 0x1FFFF;
            int rel = rc.x >> 17;
            float nm = __uint_as_float(rc.y);
            u32 q = *(const u32*)(tbl + ((size_t)rel * N_NODES + src) * OD + l * 2);
            a0 = fmaf(nm, bl16(q), a0);
            a1 = fmaf(nm, bh16(q), a1);
        }
        a0 += __shfl_xor(a0, 4);  a1 += __shfl_xor(a1, 4);
        a0 += __shfl_xor(a0, 8);  a1 += __shfl_xor(a1, 8);
        a0 += __shfl_xor(a0, 16); a1 += __shfl_xor(a1, 16);
        a0 += __shfl_xor(a0, 32); a1 += __shfl_xor(a1, 32);
        float mm = fmaxf(a0, a1);
        mm = fmaxf(mm, __shfl_xor(mm, 1));
        mm = fmaxf(mm, __shfl_xor(mm, 2));
        float e0 = __expf(a0 - mm), e1 = __expf(a1 - mm);
        float s = e0 + e1;
        s += __shfl_xor(s, 1);
        s += __shfl_xor(s, 2);
        float inv = 1.0f / s;
        if (lane < 4)
            *(float2*)(out + (size_t)d * OD + l * 2) = make_float2(e0 * inv, e1 * inv);
    }
}

// ======= L1/L2 per-edge matvec (h-tables L2-resident): bf16 weights in LDS =======

// L1: 4 edge-groups x 16 out-dims. LDS [r][h][8 u32] h-stride 12, r-stride 196 (16B aligned, 2-way max).
__global__ __launch_bounds__(NTHR) void k_l1v(const uint2* __restrict__ rec, const int* __restrict__ row_ptr,
                                              const float* __restrict__ Wr1, const float* __restrict__ h0,
                                              float* __restrict__ h1) {
    __shared__ u32 wl[N_RELS * 196];  // 39.2 KB -> 4 blocks/CU
    for (int idx = threadIdx.x; idx < N_RELS * 128; idx += NTHR) {
        int r = idx >> 7, rem = idx & 127, hh = rem >> 3, p = rem & 7;
        wl[r * 196 + hh * 12 + p] = packbf(Wr1[r * 256 + (2 * p) * 16 + hh],
                                           Wr1[r * 256 + (2 * p + 1) * 16 + hh]);
    }
    __syncthreads();
    int lane = threadIdx.x & 63;
    int g = lane >> 4, h = lane & 15;
    int wave = (blockIdx.x * NTHR + threadIdx.x) >> 6;
    int nw = (gridDim.x * NTHR) >> 6;
    const u32* whl = wl + h * 12;
    for (int d = wave; d < N_NODES; d += nw) {
        int s0 = row_ptr[d], s1 = row_ptr[d + 1];
        float acc = 0.f;
        for (int j = s0 + g; j < s1; j += 4) {
            uint2 rc = rec[j];
            int src = rc.x & 0x1FFFF;
            int rel = rc.x >> 17;
            float nm = __uint_as_float(rc.y);
            const float4* hp = (const float4*)(h0 + (size_t)src * HD);  // uniform in group
            float4 a0 = hp[0], a1 = hp[1], a2 = hp[2], a3 = hp[3];
            const uint4* wp = (const uint4*)(whl + rel * 196);
            uint4 q0 = wp[0], q1 = wp[1];
            float m = bl16(q0.x) * a0.x + bh16(q0.x) * a0.y + bl16(q0.y) * a0.z + bh16(q0.y) * a0.w +
                      bl16(q0.z) * a1.x + bh16(q0.z) * a1.y + bl16(q0.w) * a1.z + bh16(q0.w) * a1.w +
                      bl16(q1.x) * a2.x + bh16(q1.x) * a2.y + bl16(q1.y) * a2.z + bh16(q1.y) * a2.w +
                      bl16(q1.z) * a3.x + bh16(q1.z) * a3.y + bl16(q1.w) * a3.z + bh16(q1.w) * a3.w;
            acc = fmaf(nm, m, acc);
        }
        acc += __shfl_xor(acc, 16);
        acc += __shfl_xor(acc, 32);
        if (lane < 16) h1[(size_t)d * HD + lane] = fmaxf(acc, 0.f);  // fused relu
    }
}

// L2 + softmax: 8 edge-groups x 8 out-dims. LDS [r][o][8 u32] o-stride 12, r-stride 100.
__global__ __launch_bounds__(NTHR) void k_l2v(const uint2* __restrict__ rec, const int* __restrict__ row_ptr,
                                              const float* __restrict__ Wr2, const float* __restrict__ h1,
                                              float* __restrict__ out) {
    __shared__ u32 wl[N_RELS * 100];  // 20 KB
    for (int idx = threadIdx.x; idx < N_RELS * 64; idx += NTHR) {
        int r = idx >> 6, rem = idx & 63, o = rem >> 3, p = rem & 7;
        wl[r * 100 + o * 12 + p] = packbf(Wr2[r * 128 + (2 * p) * 8 + o],
                                          Wr2[r * 128 + (2 * p + 1) * 8 + o]);
    }
    __syncthreads();
    int lane = threadIdx.x & 63;
    int g = lane >> 3, o = lane & 7;
    int wave = (blockIdx.x * NTHR + threadIdx.x) >> 6;
    int nw = (gridDim.x * NTHR) >> 6;
    const u32* wol = wl + o * 12;
    for (int d = wave; d < N_NODES; d += nw) {
        int s0 = row_ptr[d], s1 = row_ptr[d + 1];
        float acc = 0.f;
        for (int j = s0 + g; j < s1; j += 8) {
            uint2 rc = rec[j];
            int src = rc.x & 0x1FFFF;
            int rel = rc.x >> 17;
            float nm = __uint_as_float(rc.y);
            const float4* hp = (const float4*)(h1 + (size_t)src * HD);
            float4 a0 = hp[0], a1 = hp[1], a2 = hp[2], a3 = hp[3];
            const uint4* wp = (const uint4*)(wol + rel * 100);
            uint4 q0 = wp[0], q1 = wp[1];
            float m = bl16(q0.x) * a0.x + bh16(q0.x) * a0.y + bl16(q0.y) * a0.z + bh16(q0.y) * a0.w +
                      bl16(q0.z) * a1.x + bh16(q0.z) * a1.y + bl16(q0.w) * a1.z + bh16(q0.w) * a1.w +
                      bl16(q1.x) * a2.x + bh16(q1.x) * a2.y + bl16(q1.y) * a2.z + bh16(q1.y) * a2.w +
                      bl16(q1.z) * a3.x + bh16(q1.z) * a3.y + bl16(q1.w) * a3.z + bh16(q1.w) * a3.w;
            acc = fmaf(nm, m, acc);
        }
        acc += __shfl_xor(acc, 8);
        acc += __shfl_xor(acc, 16);
        acc += __shfl_xor(acc, 32);
        float mx = acc;
        mx = fmaxf(mx, __shfl_xor(mx, 1));
        mx = fmaxf(mx, __shfl_xor(mx, 2));
        mx = fmaxf(mx, __shfl_xor(mx, 4));
        float ex = __expf(acc - mx);
        float sm = ex;
        sm += __shfl_xor(sm, 1);
        sm += __shfl_xor(sm, 2);
        sm += __shfl_xor(sm, 4);
        if (lane < 8) out[(size_t)d * OD + o] = ex / sm;
    }
}

// ======= TIER A : L0 via node-major bf16 W0t (fits 92 MB ws) =======

__global__ __launch_bounds__(NTHR) void k_transpose(const float* __restrict__ W0, uint4* __restrict__ W0t) {
    int t = blockIdx.x * NTHR + threadIdx.x;
    if (t >= N_NODES * HD) return;
    u32 u[8];
    #pragma unroll
    for (int k = 0; k < 8; ++k) {
        u32 a = __float_as_uint(W0[(size_t)(2 * k) * (N_NODES * HD) + t]);
        u32 b = __float_as_uint(W0[(size_t)(2 * k + 1) * (N_NODES * HD) + t]);
        a = (a + 0x7fffu + ((a >> 16) & 1u)) >> 16;
        b = (b + 0x7fffu + ((b >> 16) & 1u)) >> 16;
        u[k] = a | (b << 16);
    }
    W0t[t * 2] = make_uint4(u[0], u[1], u[2], u[3]);
    W0t[t * 2 + 1] = make_uint4(u[4], u[5], u[6], u[7]);
}

__global__ __launch_bounds__(NTHR) void k_l0s(const uint2* __restrict__ rec, const int* __restrict__ row_ptr,
                                              const float* __restrict__ C0, const uint4* __restrict__ W0t,
                                              float* __restrict__ h0) {
    int lane = threadIdx.x & 63;
    int g = lane >> 4, h = lane & 15;
    int wave = (blockIdx.x * NTHR + threadIdx.x) >> 6;
    int nw = (gridDim.x * NTHR) >> 6;
    for (int d = wave; d < N_NODES; d += nw) {
        int s0 = row_ptr[d], s1 = row_ptr[d + 1];
        float acc = 0.f;
        for (int j = s0 + g; j < s1; j += 4) {
            uint2 rc = rec[j];
            int src = rc.x & 0x1FFFF;
            int rel = rc.x >> 17;
            float nm = __uint_as_float(rc.y);
            const float4* cp = (const float4*)(C0 + rel * 16);
            float4 c0 = cp[0], c1 = cp[1], c2 = cp[2], c3 = cp[3];
            uint4 q0 = W0t[src * 32 + h * 2];
            uint4 q1 = W0t[src * 32 + h * 2 + 1];
            float m = bl16(q0.x) * c0.x + bh16(q0.x) * c0.y + bl16(q0.y) * c0.z + bh16(q0.y) * c0.w +
                      bl16(q0.z) * c1.x + bh16(q0.z) * c1.y + bl16(q0.w) * c1.z + bh16(q0.w) * c1.w +
                      bl16(q1.x) * c2.x + bh16(q1.x) * c2.y + bl16(q1.y) * c2.z + bh16(q1.y) * c2.w +
                      bl16(q1.z) * c3.x + bh16(q1.z) * c3.y + bl16(q1.w) * c3.z + bh16(q1.w) * c3.w;
            acc = fmaf(nm, m, acc);
        }
        acc += __shfl_xor(acc, 16);
        acc += __shfl_xor(acc, 32);
        if (lane < 16) h0[(size_t)d * HD + lane] = fmaxf(acc, 0.f);
    }
}

// ======= TIER B fallback (atomics, 16.1 MB) =======
#define NBLK 2560

__device__ __forceinline__ void fma4(float* acc, float c, float4 w) {
    acc[0] = fmaf(c, w.x, acc[0]);
    acc[1] = fmaf(c, w.y, acc[1]);
    acc[2] = fmaf(c, w.z, acc[2]);
    acc[3] = fmaf(c, w.w, acc[3]);
}

__global__ __launch_bounds__(NTHR) void k_l0_old(const int* __restrict__ esrc, const int* __restrict__ edst,
                                                 const int* __restrict__ erel, const float* __restrict__ enorm,
                                                 const float* __restrict__ W0, const float* __restrict__ C0,
                                                 float* __restrict__ h0) {
    for (int e = blockIdx.x * NTHR + threadIdx.x; e < E_TOTAL; e += NBLK * NTHR) {
        int s = esrc[e], d = edst[e], r = erel[e];
        float nm = enorm[e];
        const float4* cp = reinterpret_cast<const float4*>(C0 + r * N_BASES);
        float4 c0 = cp[0], c1 = cp[1], c2 = cp[2], c3 = cp[3];
        float coef[16] = {c0.x, c0.y, c0.z, c0.w, c1.x, c1.y, c1.z, c1.w,
                          c2.x, c2.y, c2.z, c2.w, c3.x, c3.y, c3.z, c3.w};
        float acc[16];
        #pragma unroll
        for (int h = 0; h < 16; ++h) acc[h] = 0.f;
        const float* wbase = W0 + (size_t)s * HD;
        #pragma unroll
        for (int b = 0; b < N_BASES; ++b) {
            const float4* wp = reinterpret_cast<const float4*>(wbase + (size_t)b * (N_NODES * HD));
            float cb = coef[b];
            fma4(acc + 0, cb, wp[0]);
            fma4(acc + 4, cb, wp[1]);
            fma4(acc + 8, cb, wp[2]);
            fma4(acc + 12, cb, wp[3]);
        }
        float* outp = h0 + (size_t)d * HD;
        #pragma unroll
        for (int h = 0; h < 16; ++h) atomicAdd(outp + h, nm * acc[h]);
    }
}

__global__ __launch_bounds__(NTHR) void k_l1_old(const int* __restrict__ esrc, const int* __restrict__ edst,
                                                 const int* __restrict__ erel, const float* __restrict__ enorm,
                                                 const float* __restrict__ h0, const float* __restrict__ Wr1,
                                                 float* __restrict__ h1) {
    __shared__ float w[N_RELS * 260];
    for (int i = threadIdx.x; i < N_RELS * 256; i += NTHR) {
        int r = i >> 8, rest = i & 255;
        w[r * 260 + rest] = Wr1[i];
    }
    __syncthreads();
    for (int e = blockIdx.x * NTHR + threadIdx.x; e < E_TOTAL; e += NBLK * NTHR) {
        int s = esrc[e], d = edst[e], r = erel[e];
        float nm = enorm[e];
        const float4* hp = reinterpret_cast<const float4*>(h0 + (size_t)s * HD);
        float4 hv0 = hp[0], hv1 = hp[1], hv2 = hp[2], hv3 = hp[3];
        float hs[16] = {fmaxf(hv0.x, 0.f), fmaxf(hv0.y, 0.f), fmaxf(hv0.z, 0.f), fmaxf(hv0.w, 0.f),
                        fmaxf(hv1.x, 0.f), fmaxf(hv1.y, 0.f), fmaxf(hv1.z, 0.f), fmaxf(hv1.w, 0.f),
                        fmaxf(hv2.x, 0.f), fmaxf(hv2.y, 0.f), fmaxf(hv2.z, 0.f), fmaxf(hv2.w, 0.f),
                        fmaxf(hv3.x, 0.f), fmaxf(hv3.y, 0.f), fmaxf(hv3.z, 0.f), fmaxf(hv3.w, 0.f)};
        float acc[16];
        #pragma unroll
        for (int h = 0; h < 16; ++h) acc[h] = 0.f;
        const float* wr = w + r * 260;
        #pragma unroll
        for (int i = 0; i < 16; ++i) {
            float hi = hs[i];
            const float4* wp = reinterpret_cast<const float4*>(wr + i * 16);
            fma4(acc + 0, hi, wp[0]);
            fma4(acc + 4, hi, wp[1]);
            fma4(acc + 8, hi, wp[2]);
            fma4(acc + 12, hi, wp[3]);
        }
        float* outp = h1 + (size_t)d * HD;
        #pragma unroll
        for (int h = 0; h < 16; ++h) atomicAdd(outp + h, nm * acc[h]);
    }
}

__global__ __launch_bounds__(NTHR) void k_l2_old(const int* __restrict__ esrc, const int* __restrict__ edst,
                                                 const int* __restrict__ erel, const float* __restrict__ enorm,
                                                 const float* __restrict__ h1, const float* __restrict__ Wr2,
                                                 float* __restrict__ h2) {
    __shared__ float w[N_RELS * 132];
    for (int i = threadIdx.x; i < N_RELS * 128; i += NTHR) {
        int r = i >> 7, rest = i & 127;
        w[r * 132 + rest] = Wr2[i];
    }
    __syncthreads();
    for (int e = blockIdx.x * NTHR + threadIdx.x; e < E_TOTAL; e += NBLK * NTHR) {
        int s = esrc[e], d = edst[e], r = erel[e];
        float nm = enorm[e];
        const float4* hp = reinterpret_cast<const float4*>(h1 + (size_t)s * HD);
        float4 hv0 = hp[0], hv1 = hp[1], hv2 = hp[2], hv3 = hp[3];
        float hs[16] = {fmaxf(hv0.x, 0.f), fmaxf(hv0.y, 0.f), fmaxf(hv0.z, 0.f), fmaxf(hv0.w, 0.f),
                        fmaxf(hv1.x, 0.f), fmaxf(hv1.y, 0.f), fmaxf(hv1.z, 0.f), fmaxf(hv1.w, 0.f),
                        fmaxf(hv2.x, 0.f), fmaxf(hv2.y, 0.f), fmaxf(hv2.z, 0.f), fmaxf(hv2.w, 0.f),
                        fmaxf(hv3.x, 0.f), fmaxf(hv3.y, 0.f), fmaxf(hv3.z, 0.f), fmaxf(hv3.w, 0.f)};
        float acc[8];
        #pragma unroll
        for (int h = 0; h < 8; ++h) acc[h] = 0.f;
        const float* wr = w + r * 132;
        #pragma unroll
        for (int i = 0; i < 16; ++i) {
            float hi = hs[i];
            const float4* wp = reinterpret_cast<const float4*>(wr + i * 8);
            fma4(acc + 0, hi, wp[0]);
            fma4(acc + 4, hi, wp[1]);
        }
        float* outp = h2 + (size_t)d * OD;
        #pragma unroll
        for (int h = 0; h < 8; ++h) atomicAdd(outp + h, nm * acc[h]);
    }
}

__global__ __launch_bounds__(NTHR) void k_softmax(const float* __restrict__ h2, float* __restrict__ out) {
    int n = blockIdx.x * NTHR + threadIdx.x;
    if (n >= N_NODES) return;
    const float4* p = reinterpret_cast<const float4*>(h2 + (size_t)n * OD);
    float4 a = p[0], b = p[1];
    float v[8] = {a.x, a.y, a.z, a.w, b.x, b.y, b.z, b.w};
    float m = v[0];
    #pragma unroll
    for (int i = 1; i < 8; ++i) m = fmaxf(m, v[i]);
    float ssum = 0.f;
    #pragma unroll
    for (int i = 0; i < 8; ++i) {
        v[i] = __expf(v[i] - m);
        ssum += v[i];
    }
    float inv = 1.0f / ssum;
    float4* q = reinterpret_cast<float4*>(out + (size_t)n * OD);
    q[0] = make_float4(v[0] * inv, v[1] * inv, v[2] * inv, v[3] * inv);
    q[1] = make_float4(v[4] * inv, v[5] * inv, v[6] * inv, v[7] * inv);
}

// =========================================================================

extern "C" void kernel_launch(void* const* d_in, const int* in_sizes, int n_in,
                              void* d_out, int out_size, void* d_ws, size_t ws_size,
                              hipStream_t stream) {
    const int* esrc = (const int*)d_in[0];
    const int* edst = (const int*)d_in[1];
    const int* erel = (const int*)d_in[2];
    const float* enorm = (const float*)d_in[3];
    const float* W0 = (const float*)d_in[4];
    const float* C0 = (const float*)d_in[5];
    const float* W1 = (const float*)d_in[6];
    const float* C1 = (const float*)d_in[7];
    const float* W2 = (const float*)d_in[8];
    const float* C2 = (const float*)d_in[9];
    const int nsb = (N_NODES + NTHR - 1) / NTHR;  // 391

    if (ws_size >= (size_t)201000000) {
        // ---- Tier A+: dense emb tables (emb buffer reused across layers) ----
        char* wsb = (char*)d_ws;
        ushort* emb = (ushort*)wsb;                       // 160,000,000 B (L0/L1: 160MB, L2: 80MB)
        uint2* rec = (uint2*)(wsb + 160000000);           //  25,600,000
        float* h0 = (float*)(wsb + 185600000);            //   6,400,000
        float* h1 = (float*)(wsb + 192000000);            //   6,400,000
        float* Wr1 = (float*)(wsb + 198400000);           //      51,200
        float* Wr2 = (float*)(wsb + 198451200);           //      25,600
        int* cnt = (int*)(wsb + 198476800);               //     400,000
        int* bsum = (int*)(wsb + 198876800);              //       2,048
        int* excl = (int*)(wsb + 198878848);              //     400,000
        int* row_ptr = (int*)(wsb + 199278848);           //     400,004
        int* head = (int*)(wsb + 199678852);              //     400,000

        hipMemsetAsync(cnt, 0, N_NODES * sizeof(int), stream);
        k_hist<<<E_TOTAL / NTHR, NTHR, 0, stream>>>(edst, cnt);
        k_scan1<<<nsb, NTHR, 0, stream>>>(cnt, excl, bsum);
        k_scan2<<<1, 512, 0, stream>>>(bsum, nsb);
        k_scan3<<<nsb, NTHR, 0, stream>>>(excl, bsum, row_ptr, head);
        k_scatter<<<E_TOTAL / NTHR, NTHR, 0, stream>>>(esrc, edst, erel, enorm, head, rec);
        k_wr<<<75, NTHR, 0, stream>>>(W1, C1, W2, C2, Wr1, Wr2);

        k_emb0<<<N_NODES * HD / NTHR, NTHR, 0, stream>>>(W0, C0, emb);
        k_g16<<<6250, NTHR, 0, stream>>>(rec, row_ptr, emb, h0);
        k_emb1<<<N_RELS * 391, NTHR, 0, stream>>>(Wr1, h0, emb);
        k_g16<<<6250, NTHR, 0, stream>>>(rec, row_ptr, emb, h1);
        k_emb2<<<N_RELS * 391, NTHR, 0, stream>>>(Wr2, h1, emb);
        k_g8sm<<<6250, NTHR, 0, stream>>>(rec, row_ptr, emb, (float*)d_out);
    } else if (ws_size >= (size_t)92000000) {
        // ---- Tier A: W0t gather L0 + improved L1/L2 ----
        char* wsb = (char*)d_ws;
        uint4* W0t = (uint4*)wsb;                         // 51,200,000
        uint2* rec = (uint2*)(wsb + 51200000);            // 25,600,000
        float* h0 = (float*)(wsb + 76800000);             //  6,400,000
        float* h1 = (float*)(wsb + 83200000);             //  6,400,000
        float* Wr1 = (float*)(wsb + 89600000);            //     51,200
        float* Wr2 = (float*)(wsb + 89651200);            //     25,600
        int* cnt = (int*)(wsb + 89676800);
        int* bsum = (int*)(wsb + 90076800);
        int* excl = (int*)(wsb + 90078848);
        int* row_ptr = (int*)(wsb + 90478848);
        int* head = (int*)(wsb + 90878852);

        hipMemsetAsync(cnt, 0, N_NODES * sizeof(int), stream);
        k_transpose<<<(N_NODES * HD) / NTHR, NTHR, 0, stream>>>(W0, W0t);
        k_hist<<<E_TOTAL / NTHR, NTHR, 0, stream>>>(edst, cnt);
        k_scan1<<<nsb, NTHR, 0, stream>>>(cnt, excl, bsum);
        k_scan2<<<1, 512, 0, stream>>>(bsum, nsb);
        k_scan3<<<nsb, NTHR, 0, stream>>>(excl, bsum, row_ptr, head);
        k_scatter<<<E_TOTAL / NTHR, NTHR, 0, stream>>>(esrc, edst, erel, enorm, head, rec);
        k_wr<<<75, NTHR, 0, stream>>>(W1, C1, W2, C2, Wr1, Wr2);

        k_l0s<<<12500, NTHR, 0, stream>>>(rec, row_ptr, C0, W0t, h0);
        k_l1v<<<4096, NTHR, 0, stream>>>(rec, row_ptr, Wr1, h0, h1);
        k_l2v<<<4096, NTHR, 0, stream>>>(rec, row_ptr, Wr2, h1, (float*)d_out);
    } else {
        // ---- Tier B: atomics fallback ----
        float* ws = (float*)d_ws;
        float* h0 = ws;
        float* h1 = ws + 1600000;
        float* h2 = ws + 3200000;
        float* Wr1 = ws + 4000000;
        float* Wr2 = ws + 4012800;

        hipMemsetAsync(h0, 0, (size_t)4000000 * sizeof(float), stream);
        k_wr<<<75, NTHR, 0, stream>>>(W1, C1, W2, C2, Wr1, Wr2);
        k_l0_old<<<NBLK, NTHR, 0, stream>>>(esrc, edst, erel, enorm, W0, C0, h0);
        k_l1_old<<<NBLK, NTHR, 0, stream>>>(esrc, edst, erel, enorm, h0, Wr1, h1);
        k_l2_old<<<NBLK, NTHR, 0, stream>>>(esrc, edst, erel, enorm, h1, Wr2, h2);
        k_softmax<<<nsb, NTHR, 0, stream>>>(h2, (float*)d_out);
    }
}

// Round 4
// 542.885 us; speedup vs baseline: 12.7615x; 1.2997x over previous
//
#include <hip/hip_runtime.h>
#include <cstddef>
#include <cstdint>

#define E_TOTAL 3200000
#define N_NODES 100000
#define N_RELS 50
#define N_BASES 16
#define HD 16
#define OD 8
#define NTHR 256

#define NBKT 196      // coarse buckets: dst >> 9 (512 dsts each)
#define BKT_CAP 18000 // mean 16384, sd 128 -> 12.6 sigma headroom
#define P1_BLOCKS 256
#define P1_CHUNK 12500

typedef unsigned int u32;

__device__ __forceinline__ float bl16(u32 u) { return __uint_as_float(u << 16); }
__device__ __forceinline__ float bh16(u32 u) { return __uint_as_float(u & 0xffff0000u); }
__device__ __forceinline__ u32 packbf(float x0, float x1) {
    u32 a = __float_as_uint(x0), b = __float_as_uint(x1);
    a = (a + 0x7fffu + ((a >> 16) & 1u)) >> 16;
    b = (b + 0x7fffu + ((b >> 16) & 1u)) >> 16;
    return a | (b << 16);
}

// ---------------- basis-combined dense weights (fp32, in ws) ----------------
__global__ __launch_bounds__(NTHR) void k_wr(const float* __restrict__ W1, const float* __restrict__ C1,
                                             const float* __restrict__ W2, const float* __restrict__ C2,
                                             float* __restrict__ Wr1, float* __restrict__ Wr2) {
    int idx = blockIdx.x * NTHR + threadIdx.x;
    const int n1 = N_RELS * 256;
    if (idx < n1) {
        int r = idx >> 8, io = idx & 255;
        float acc = 0.f;
        #pragma unroll
        for (int b = 0; b < N_BASES; ++b)
            acc = fmaf(C1[r * N_BASES + b], W1[b * 256 + io], acc);
        Wr1[idx] = acc;
    } else if (idx < n1 + N_RELS * 128) {
        int j = idx - n1;
        int r = j >> 7, io = j & 127;
        float acc = 0.f;
        #pragma unroll
        for (int b = 0; b < N_BASES; ++b)
            acc = fmaf(C2[r * N_BASES + b], W2[b * 128 + io], acc);
        Wr2[j] = acc;
    }
}

// ================= two-level dst-sort (write-amplification-free) =================

// Pass 1: coarse partition into NBKT buckets. Per-block LDS hist -> one global
// atomic reserve per bucket per block -> records written as contiguous runs.
__global__ __launch_bounds__(NTHR) void k_p1(const int* __restrict__ esrc, const int* __restrict__ edst,
                                             const int* __restrict__ erel, const float* __restrict__ enorm,
                                             int* __restrict__ bhead, uint2* __restrict__ tmp) {
    __shared__ int lcnt[NBKT], lbase[NBKT], lcur[NBKT];
    int tid = threadIdx.x;
    for (int i = tid; i < NBKT; i += NTHR) { lcnt[i] = 0; lcur[i] = 0; }
    __syncthreads();
    int e0 = blockIdx.x * P1_CHUNK;
    for (int i = tid; i < P1_CHUNK; i += NTHR)
        atomicAdd(&lcnt[edst[e0 + i] >> 9], 1);
    __syncthreads();
    for (int i = tid; i < NBKT; i += NTHR)
        lbase[i] = atomicAdd(&bhead[i], lcnt[i]);
    __syncthreads();
    for (int i = tid; i < P1_CHUNK; i += NTHR) {
        int e = e0 + i;
        int d = edst[e];
        int b = d >> 9;
        int pos = b * BKT_CAP + lbase[b] + atomicAdd(&lcur[b], 1);
        tmp[pos] = make_uint2((u32)esrc[e] | ((u32)erel[e] << 17) | ((u32)(d & 511) << 23),
                              __float_as_uint(enorm[e]));
    }
}

// scan of NBKT bucket counts -> global base of each bucket in final rec
__global__ void k_bscan(const int* __restrict__ bhead, int* __restrict__ bfinal) {
    __shared__ int s[256];
    int tid = threadIdx.x;
    int v = (tid < NBKT) ? bhead[tid] : 0;
    s[tid] = v;
    __syncthreads();
    for (int off = 1; off < 256; off <<= 1) {
        int t = (tid >= off) ? s[tid - off] : 0;
        __syncthreads();
        s[tid] += t;
        __syncthreads();
    }
    if (tid < NBKT) bfinal[tid] = s[tid] - v;  // exclusive
}

// Pass 2: one block per bucket. LDS per-dst hist (512 counters) + LDS scan ->
// row_ptr written directly; scatter confined to the bucket's ~131 KB L2 window.
__global__ __launch_bounds__(NTHR) void k_p2(const uint2* __restrict__ tmp, const int* __restrict__ bhead,
                                             const int* __restrict__ bfinal, uint2* __restrict__ rec,
                                             int* __restrict__ row_ptr) {
    int b = blockIdx.x;
    int cnt = bhead[b];
    int gbase = bfinal[b];
    __shared__ int dcnt[512], dscan[512];
    int tid = threadIdx.x;
    dcnt[tid] = 0;
    dcnt[tid + 256] = 0;
    __syncthreads();
    const uint2* tb = tmp + (size_t)b * BKT_CAP;
    for (int i = tid; i < cnt; i += NTHR)
        atomicAdd(&dcnt[tb[i].x >> 23], 1);
    __syncthreads();
    dscan[tid] = dcnt[tid];
    dscan[tid + 256] = dcnt[tid + 256];
    __syncthreads();
    for (int off = 1; off < 512; off <<= 1) {
        int v0 = (tid >= off) ? dscan[tid - off] : 0;
        int v1 = (tid + 256 >= off) ? dscan[tid + 256 - off] : 0;
        __syncthreads();
        dscan[tid] += v0;
        dscan[tid + 256] += v1;
        __syncthreads();
    }
    int d0 = b << 9;
    #pragma unroll
    for (int k = 0; k < 2; ++k) {
        int dl = tid + k * 256;
        int excl = gbase + dscan[dl] - dcnt[dl];
        int d = d0 + dl;
        if (d < N_NODES) row_ptr[d] = excl;
        dscan[dl] = excl;  // becomes the scatter cursor
    }
    if (b == NBKT - 1 && tid == 0) row_ptr[N_NODES] = E_TOTAL;
    __syncthreads();
    for (int i = tid; i < cnt; i += NTHR) {
        uint2 t = tb[i];
        int pos = atomicAdd(&dscan[t.x >> 23], 1);
        rec[pos] = make_uint2(t.x & 0x7FFFFFu, t.y);
    }
}

// ================= TIER A+ : dense embedding tables =================

// emb0[r][n][h] = sum_b C0[r,b]*W0[b,n,h], bf16.
__global__ __launch_bounds__(NTHR) void k_emb0(const float* __restrict__ W0, const float* __restrict__ C0,
                                               ushort* __restrict__ emb) {
    int t = threadIdx.x;
    size_t base = (size_t)blockIdx.x * 256 + t;  // n*16+h
    float w[16];
    #pragma unroll
    for (int b = 0; b < 16; ++b) w[b] = W0[(size_t)b * (N_NODES * HD) + base];
    __shared__ float c[N_RELS * 16];
    for (int i = t; i < N_RELS * 16; i += NTHR) c[i] = C0[i];
    __syncthreads();
    for (int r = 0; r < N_RELS; ++r) {
        const float* cr = c + r * 16;
        float v = 0.f;
        #pragma unroll
        for (int b = 0; b < 16; ++b) v = fmaf(cr[b], w[b], v);
        u32 x = __float_as_uint(v);
        x = (x + 0x7fffu + ((x >> 16) & 1u)) >> 16;
        emb[(size_t)r * (N_NODES * HD) + base] = (ushort)x;
    }
}

// gather-accumulate 16-dim bf16 rows by (rel,src), relu-fused, fp32 out.
__global__ __launch_bounds__(NTHR) void k_g16(const uint2* __restrict__ rec, const int* __restrict__ row_ptr,
                                              const ushort* __restrict__ tbl, float* __restrict__ out) {
    int lane = threadIdx.x & 63;
    int g = lane >> 3, l = lane & 7;
    int wave = (blockIdx.x * NTHR + threadIdx.x) >> 6;
    int nw = (gridDim.x * NTHR) >> 6;
    for (int d = wave; d < N_NODES; d += nw) {
        int s0 = row_ptr[d], s1 = row_ptr[d + 1];
        float a0 = 0.f, a1 = 0.f;
        for (int j = s0 + g; j < s1; j += 8) {
            uint2 rc = rec[j];
            int src = rc.x & 0x1FFFF;
            int rel = rc.x >> 17;
            float nm = __uint_as_float(rc.y);
            u32 q = *(const u32*)(tbl + ((size_t)rel * N_NODES + src) * HD + l * 2);
            a0 = fmaf(nm, bl16(q), a0);
            a1 = fmaf(nm, bh16(q), a1);
        }
        a0 += __shfl_xor(a0, 8);  a1 += __shfl_xor(a1, 8);
        a0 += __shfl_xor(a0, 16); a1 += __shfl_xor(a1, 16);
        a0 += __shfl_xor(a0, 32); a1 += __shfl_xor(a1, 32);
        if (lane < 8)
            *(float2*)(out + (size_t)d * HD + l * 2) = make_float2(fmaxf(a0, 0.f), fmaxf(a1, 0.f));
    }
}

// emb1[r][n][o] = sum_i h[n,i]*Wr1[r,i,o], bf16 out.
__global__ __launch_bounds__(NTHR) void k_emb1(const float* __restrict__ Wr1, const float* __restrict__ h,
                                               ushort* __restrict__ emb) {
    int r = blockIdx.x / 391, tile = blockIdx.x % 391;
    __shared__ float w[256];
    w[threadIdx.x] = Wr1[r * 256 + threadIdx.x];
    __syncthreads();
    int n = tile * NTHR + threadIdx.x;
    if (n >= N_NODES) return;
    const float4* hp = (const float4*)(h + (size_t)n * HD);
    float4 a0 = hp[0], a1 = hp[1], a2 = hp[2], a3 = hp[3];
    float hv[16] = {a0.x, a0.y, a0.z, a0.w, a1.x, a1.y, a1.z, a1.w,
                    a2.x, a2.y, a2.z, a2.w, a3.x, a3.y, a3.z, a3.w};
    float acc[16];
    #pragma unroll
    for (int o = 0; o < 16; ++o) acc[o] = 0.f;
    #pragma unroll
    for (int i = 0; i < 16; ++i) {
        const float4* wp = (const float4*)(w + i * 16);
        float4 w0 = wp[0], w1 = wp[1], w2 = wp[2], w3 = wp[3];
        float hi = hv[i];
        acc[0] = fmaf(hi, w0.x, acc[0]);   acc[1] = fmaf(hi, w0.y, acc[1]);
        acc[2] = fmaf(hi, w0.z, acc[2]);   acc[3] = fmaf(hi, w0.w, acc[3]);
        acc[4] = fmaf(hi, w1.x, acc[4]);   acc[5] = fmaf(hi, w1.y, acc[5]);
        acc[6] = fmaf(hi, w1.z, acc[6]);   acc[7] = fmaf(hi, w1.w, acc[7]);
        acc[8] = fmaf(hi, w2.x, acc[8]);   acc[9] = fmaf(hi, w2.y, acc[9]);
        acc[10] = fmaf(hi, w2.z, acc[10]); acc[11] = fmaf(hi, w2.w, acc[11]);
        acc[12] = fmaf(hi, w3.x, acc[12]); acc[13] = fmaf(hi, w3.y, acc[13]);
        acc[14] = fmaf(hi, w3.z, acc[14]); acc[15] = fmaf(hi, w3.w, acc[15]);
    }
    u32 p[8];
    #pragma unroll
    for (int k = 0; k < 8; ++k) p[k] = packbf(acc[2 * k], acc[2 * k + 1]);
    uint4* op = (uint4*)(emb + ((size_t)r * N_NODES + n) * HD);
    op[0] = make_uint4(p[0], p[1], p[2], p[3]);
    op[1] = make_uint4(p[4], p[5], p[6], p[7]);
}

// emb2[r][n][o] = sum_i h[n,i]*Wr2[r,i,o] (o<8), bf16 out.
__global__ __launch_bounds__(NTHR) void k_emb2(const float* __restrict__ Wr2, const float* __restrict__ h,
                                               ushort* __restrict__ emb) {
    int r = blockIdx.x / 391, tile = blockIdx.x % 391;
    __shared__ float w[128];
    if (threadIdx.x < 128) w[threadIdx.x] = Wr2[r * 128 + threadIdx.x];
    __syncthreads();
    int n = tile * NTHR + threadIdx.x;
    if (n >= N_NODES) return;
    const float4* hp = (const float4*)(h + (size_t)n * HD);
    float4 a0 = hp[0], a1 = hp[1], a2 = hp[2], a3 = hp[3];
    float hv[16] = {a0.x, a0.y, a0.z, a0.w, a1.x, a1.y, a1.z, a1.w,
                    a2.x, a2.y, a2.z, a2.w, a3.x, a3.y, a3.z, a3.w};
    float acc[8];
    #pragma unroll
    for (int o = 0; o < 8; ++o) acc[o] = 0.f;
    #pragma unroll
    for (int i = 0; i < 16; ++i) {
        const float4* wp = (const float4*)(w + i * 8);
        float4 w0 = wp[0], w1 = wp[1];
        float hi = hv[i];
        acc[0] = fmaf(hi, w0.x, acc[0]); acc[1] = fmaf(hi, w0.y, acc[1]);
        acc[2] = fmaf(hi, w0.z, acc[2]); acc[3] = fmaf(hi, w0.w, acc[3]);
        acc[4] = fmaf(hi, w1.x, acc[4]); acc[5] = fmaf(hi, w1.y, acc[5]);
        acc[6] = fmaf(hi, w1.z, acc[6]); acc[7] = fmaf(hi, w1.w, acc[7]);
    }
    u32 p[4];
    #pragma unroll
    for (int k = 0; k < 4; ++k) p[k] = packbf(acc[2 * k], acc[2 * k + 1]);
    *(uint4*)(emb + ((size_t)r * N_NODES + n) * OD) = make_uint4(p[0], p[1], p[2], p[3]);
}

// gather 8-dim bf16 rows + fused softmax.
__global__ __launch_bounds__(NTHR) void k_g8sm(const uint2* __restrict__ rec, const int* __restrict__ row_ptr,
                                               const ushort* __restrict__ tbl, float* __restrict__ out) {
    int lane = threadIdx.x & 63;
    int g = lane >> 2, l = lane & 3;
    int wave = (blockIdx.x * NTHR + threadIdx.x) >> 6;
    int nw = (gridDim.x * NTHR) >> 6;
    for (int d = wave; d < N_NODES; d += nw) {
        int s0 = row_ptr[d], s1 = row_ptr[d + 1];
        float a0 = 0.f, a1 = 0.f;
        for (int j = s0 + g; j < s1; j += 16) {
            uint2 rc = rec[j];
            int src = rc.x & 0x1FFFF;
            int rel = rc.x >> 17;
            float nm = __uint_as_float(rc.y);
            u32 q = *(const u32*)(tbl + ((size_t)rel * N_NODES + src) * OD + l * 2);
            a0 = fmaf(nm, bl16(q), a0);
            a1 = fmaf(nm, bh16(q), a1);
        }
        a0 += __shfl_xor(a0, 4);  a1 += __shfl_xor(a1, 4);
        a0 += __shfl_xor(a0, 8);  a1 += __shfl_xor(a1, 8);
        a0 += __shfl_xor(a0, 16); a1 += __shfl_xor(a1, 16);
        a0 += __shfl_xor(a0, 32); a1 += __shfl_xor(a1, 32);
        float mm = fmaxf(a0, a1);
        mm = fmaxf(mm, __shfl_xor(mm, 1));
        mm = fmaxf(mm, __shfl_xor(mm, 2));
        float e0 = __expf(a0 - mm), e1 = __expf(a1 - mm);
        float s = e0 + e1;
        s += __shfl_xor(s, 1);
        s += __shfl_xor(s, 2);
        float inv = 1.0f / s;
        if (lane < 4)
            *(float2*)(out + (size_t)d * OD + l * 2) = make_float2(e0 * inv, e1 * inv);
    }
}

// ================= TIER A (92 MB) legacy sort pipeline + kernels =================

__global__ __launch_bounds__(NTHR) void k_hist(const int* __restrict__ edst, int* __restrict__ cnt) {
    int e = blockIdx.x * NTHR + threadIdx.x;
    if (e < E_TOTAL) atomicAdd(&cnt[edst[e]], 1);
}

__global__ __launch_bounds__(NTHR) void k_scan1(const int* __restrict__ cnt, int* __restrict__ excl,
                                                int* __restrict__ bsum) {
    __shared__ int s[NTHR];
    int i = blockIdx.x * NTHR + threadIdx.x;
    int v = (i < N_NODES) ? cnt[i] : 0;
    s[threadIdx.x] = v;
    __syncthreads();
    #pragma unroll
    for (int off = 1; off < NTHR; off <<= 1) {
        int t = (threadIdx.x >= off) ? s[threadIdx.x - off] : 0;
        __syncthreads();
        s[threadIdx.x] += t;
        __syncthreads();
    }
    if (i < N_NODES) excl[i] = s[threadIdx.x] - v;
    if (threadIdx.x == NTHR - 1) bsum[blockIdx.x] = s[NTHR - 1];
}

__global__ void k_scan2(int* __restrict__ bsum, int nb) {
    __shared__ int s[512];
    int tid = threadIdx.x;
    int v = (tid < nb) ? bsum[tid] : 0;
    s[tid] = v;
    __syncthreads();
    for (int off = 1; off < 512; off <<= 1) {
        int t = (tid >= off) ? s[tid - off] : 0;
        __syncthreads();
        s[tid] += t;
        __syncthreads();
    }
    if (tid < nb) bsum[tid] = s[tid] - v;
}

__global__ __launch_bounds__(NTHR) void k_scan3(const int* __restrict__ excl, const int* __restrict__ bsum,
                                                int* __restrict__ row_ptr, int* __restrict__ head) {
    int i = blockIdx.x * NTHR + threadIdx.x;
    if (i < N_NODES) {
        int v = excl[i] + bsum[blockIdx.x];
        row_ptr[i] = v;
        head[i] = v;
    }
    if (i == 0) row_ptr[N_NODES] = E_TOTAL;
}

__global__ __launch_bounds__(NTHR) void k_scatter(const int* __restrict__ esrc, const int* __restrict__ edst,
                                                  const int* __restrict__ erel, const float* __restrict__ enorm,
                                                  int* __restrict__ head, uint2* __restrict__ rec) {
    int e = blockIdx.x * NTHR + threadIdx.x;
    if (e >= E_TOTAL) return;
    int d = edst[e];
    int pos = atomicAdd(&head[d], 1);
    u32 sr = (u32)esrc[e] | ((u32)erel[e] << 17);
    rec[pos] = make_uint2(sr, __float_as_uint(enorm[e]));
}

__global__ __launch_bounds__(NTHR) void k_transpose(const float* __restrict__ W0, uint4* __restrict__ W0t) {
    int t = blockIdx.x * NTHR + threadIdx.x;
    if (t >= N_NODES * HD) return;
    u32 u[8];
    #pragma unroll
    for (int k = 0; k < 8; ++k) {
        u32 a = __float_as_uint(W0[(size_t)(2 * k) * (N_NODES * HD) + t]);
        u32 b = __float_as_uint(W0[(size_t)(2 * k + 1) * (N_NODES * HD) + t]);
        a = (a + 0x7fffu + ((a >> 16) & 1u)) >> 16;
        b = (b + 0x7fffu + ((b >> 16) & 1u)) >> 16;
        u[k] = a | (b << 16);
    }
    W0t[t * 2] = make_uint4(u[0], u[1], u[2], u[3]);
    W0t[t * 2 + 1] = make_uint4(u[4], u[5], u[6], u[7]);
}

__global__ __launch_bounds__(NTHR) void k_l0s(const uint2* __restrict__ rec, const int* __restrict__ row_ptr,
                                              const float* __restrict__ C0, const uint4* __restrict__ W0t,
                                              float* __restrict__ h0) {
    int lane = threadIdx.x & 63;
    int g = lane >> 4, h = lane & 15;
    int wave = (blockIdx.x * NTHR + threadIdx.x) >> 6;
    int nw = (gridDim.x * NTHR) >> 6;
    for (int d = wave; d < N_NODES; d += nw) {
        int s0 = row_ptr[d], s1 = row_ptr[d + 1];
        float acc = 0.f;
        for (int j = s0 + g; j < s1; j += 4) {
            uint2 rc = rec[j];
            int src = rc.x & 0x1FFFF;
            int rel = rc.x >> 17;
            float nm = __uint_as_float(rc.y);
            const float4* cp = (const float4*)(C0 + rel * 16);
            float4 c0 = cp[0], c1 = cp[1], c2 = cp[2], c3 = cp[3];
            uint4 q0 = W0t[src * 32 + h * 2];
            uint4 q1 = W0t[src * 32 + h * 2 + 1];
            float m = bl16(q0.x) * c0.x + bh16(q0.x) * c0.y + bl16(q0.y) * c0.z + bh16(q0.y) * c0.w +
                      bl16(q0.z) * c1.x + bh16(q0.z) * c1.y + bl16(q0.w) * c1.z + bh16(q0.w) * c1.w +
                      bl16(q1.x) * c2.x + bh16(q1.x) * c2.y + bl16(q1.y) * c2.z + bh16(q1.y) * c2.w +
                      bl16(q1.z) * c3.x + bh16(q1.z) * c3.y + bl16(q1.w) * c3.z + bh16(q1.w) * c3.w;
            acc = fmaf(nm, m, acc);
        }
        acc += __shfl_xor(acc, 16);
        acc += __shfl_xor(acc, 32);
        if (lane < 16) h0[(size_t)d * HD + lane] = fmaxf(acc, 0.f);
    }
}

__global__ __launch_bounds__(NTHR) void k_l1v(const uint2* __restrict__ rec, const int* __restrict__ row_ptr,
                                              const float* __restrict__ Wr1, const float* __restrict__ h0,
                                              float* __restrict__ h1) {
    __shared__ u32 wl[N_RELS * 196];
    for (int idx = threadIdx.x; idx < N_RELS * 128; idx += NTHR) {
        int r = idx >> 7, rem = idx & 127, hh = rem >> 3, p = rem & 7;
        wl[r * 196 + hh * 12 + p] = packbf(Wr1[r * 256 + (2 * p) * 16 + hh],
                                           Wr1[r * 256 + (2 * p + 1) * 16 + hh]);
    }
    __syncthreads();
    int lane = threadIdx.x & 63;
    int g = lane >> 4, h = lane & 15;
    int wave = (blockIdx.x * NTHR + threadIdx.x) >> 6;
    int nw = (gridDim.x * NTHR) >> 6;
    const u32* whl = wl + h * 12;
    for (int d = wave; d < N_NODES; d += nw) {
        int s0 = row_ptr[d], s1 = row_ptr[d + 1];
        float acc = 0.f;
        for (int j = s0 + g; j < s1; j += 4) {
            uint2 rc = rec[j];
            int src = rc.x & 0x1FFFF;
            int rel = rc.x >> 17;
            float nm = __uint_as_float(rc.y);
            const float4* hp = (const float4*)(h0 + (size_t)src * HD);
            float4 a0 = hp[0], a1 = hp[1], a2 = hp[2], a3 = hp[3];
            const uint4* wp = (const uint4*)(whl + rel * 196);
            uint4 q0 = wp[0], q1 = wp[1];
            float m = bl16(q0.x) * a0.x + bh16(q0.x) * a0.y + bl16(q0.y) * a0.z + bh16(q0.y) * a0.w +
                      bl16(q0.z) * a1.x + bh16(q0.z) * a1.y + bl16(q0.w) * a1.z + bh16(q0.w) * a1.w +
                      bl16(q1.x) * a2.x + bh16(q1.x) * a2.y + bl16(q1.y) * a2.z + bh16(q1.y) * a2.w +
                      bl16(q1.z) * a3.x + bh16(q1.z) * a3.y + bl16(q1.w) * a3.z + bh16(q1.w) * a3.w;
            acc = fmaf(nm, m, acc);
        }
        acc += __shfl_xor(acc, 16);
        acc += __shfl_xor(acc, 32);
        if (lane < 16) h1[(size_t)d * HD + lane] = fmaxf(acc, 0.f);
    }
}

__global__ __launch_bounds__(NTHR) void k_l2v(const uint2* __restrict__ rec, const int* __restrict__ row_ptr,
                                              const float* __restrict__ Wr2, const float* __restrict__ h1,
                                              float* __restrict__ out) {
    __shared__ u32 wl[N_RELS * 100];
    for (int idx = threadIdx.x; idx < N_RELS * 64; idx += NTHR) {
        int r = idx >> 6, rem = idx & 63, o = rem >> 3, p = rem & 7;
        wl[r * 100 + o * 12 + p] = packbf(Wr2[r * 128 + (2 * p) * 8 + o],
                                          Wr2[r * 128 + (2 * p + 1) * 8 + o]);
    }
    __syncthreads();
    int lane = threadIdx.x & 63;
    int g = lane >> 3, o = lane & 7;
    int wave = (blockIdx.x * NTHR + threadIdx.x) >> 6;
    int nw = (gridDim.x * NTHR) >> 6;
    const u32* wol = wl + o * 12;
    for (int d = wave; d < N_NODES; d += nw) {
        int s0 = row_ptr[d], s1 = row_ptr[d + 1];
        float acc = 0.f;
        for (int j = s0 + g; j < s1; j += 8) {
            uint2 rc = rec[j];
            int src = rc.x & 0x1FFFF;
            int rel = rc.x >> 17;
            float nm = __uint_as_float(rc.y);
            const float4* hp = (const float4*)(h1 + (size_t)src * HD);
            float4 a0 = hp[0], a1 = hp[1], a2 = hp[2], a3 = hp[3];
            const uint4* wp = (const uint4*)(wol + rel * 100);
            uint4 q0 = wp[0], q1 = wp[1];
            float m = bl16(q0.x) * a0.x + bh16(q0.x) * a0.y + bl16(q0.y) * a0.z + bh16(q0.y) * a0.w +
                      bl16(q0.z) * a1.x + bh16(q0.z) * a1.y + bl16(q0.w) * a1.z + bh16(q0.w) * a1.w +
                      bl16(q1.x) * a2.x + bh16(q1.x) * a2.y + bl16(q1.y) * a2.z + bh16(q1.y) * a2.w +
                      bl16(q1.z) * a3.x + bh16(q1.z) * a3.y + bl16(q1.w) * a3.z + bh16(q1.w) * a3.w;
            acc = fmaf(nm, m, acc);
        }
        acc += __shfl_xor(acc, 8);
        acc += __shfl_xor(acc, 16);
        acc += __shfl_xor(acc, 32);
        float mx = acc;
        mx = fmaxf(mx, __shfl_xor(mx, 1));
        mx = fmaxf(mx, __shfl_xor(mx, 2));
        mx = fmaxf(mx, __shfl_xor(mx, 4));
        float ex = __expf(acc - mx);
        float sm = ex;
        sm += __shfl_xor(sm, 1);
        sm += __shfl_xor(sm, 2);
        sm += __shfl_xor(sm, 4);
        if (lane < 8) out[(size_t)d * OD + o] = ex / sm;
    }
}

// ======= TIER B fallback (atomics, 16.1 MB) =======
#define NBLK 2560

__device__ __forceinline__ void fma4(float* acc, float c, float4 w) {
    acc[0] = fmaf(c, w.x, acc[0]);
    acc[1] = fmaf(c, w.y, acc[1]);
    acc[2] = fmaf(c, w.z, acc[2]);
    acc[3] = fmaf(c, w.w, acc[3]);
}

__global__ __launch_bounds__(NTHR) void k_l0_old(const int* __restrict__ esrc, const int* __restrict__ edst,
                                                 const int* __restrict__ erel, const float* __restrict__ enorm,
                                                 const float* __restrict__ W0, const float* __restrict__ C0,
                                                 float* __restrict__ h0) {
    for (int e = blockIdx.x * NTHR + threadIdx.x; e < E_TOTAL; e += NBLK * NTHR) {
        int s = esrc[e], d = edst[e], r = erel[e];
        float nm = enorm[e];
        const float4* cp = reinterpret_cast<const float4*>(C0 + r * N_BASES);
        float4 c0 = cp[0], c1 = cp[1], c2 = cp[2], c3 = cp[3];
        float coef[16] = {c0.x, c0.y, c0.z, c0.w, c1.x, c1.y, c1.z, c1.w,
                          c2.x, c2.y, c2.z, c2.w, c3.x, c3.y, c3.z, c3.w};
        float acc[16];
        #pragma unroll
        for (int h = 0; h < 16; ++h) acc[h] = 0.f;
        const float* wbase = W0 + (size_t)s * HD;
        #pragma unroll
        for (int b = 0; b < N_BASES; ++b) {
            const float4* wp = reinterpret_cast<const float4*>(wbase + (size_t)b * (N_NODES * HD));
            float cb = coef[b];
            fma4(acc + 0, cb, wp[0]);
            fma4(acc + 4, cb, wp[1]);
            fma4(acc + 8, cb, wp[2]);
            fma4(acc + 12, cb, wp[3]);
        }
        float* outp = h0 + (size_t)d * HD;
        #pragma unroll
        for (int h = 0; h < 16; ++h) atomicAdd(outp + h, nm * acc[h]);
    }
}

__global__ __launch_bounds__(NTHR) void k_l1_old(const int* __restrict__ esrc, const int* __restrict__ edst,
                                                 const int* __restrict__ erel, const float* __restrict__ enorm,
                                                 const float* __restrict__ h0, const float* __restrict__ Wr1,
                                                 float* __restrict__ h1) {
    __shared__ float w[N_RELS * 260];
    for (int i = threadIdx.x; i < N_RELS * 256; i += NTHR) {
        int r = i >> 8, rest = i & 255;
        w[r * 260 + rest] = Wr1[i];
    }
    __syncthreads();
    for (int e = blockIdx.x * NTHR + threadIdx.x; e < E_TOTAL; e += NBLK * NTHR) {
        int s = esrc[e], d = edst[e], r = erel[e];
        float nm = enorm[e];
        const float4* hp = reinterpret_cast<const float4*>(h0 + (size_t)s * HD);
        float4 hv0 = hp[0], hv1 = hp[1], hv2 = hp[2], hv3 = hp[3];
        float hs[16] = {fmaxf(hv0.x, 0.f), fmaxf(hv0.y, 0.f), fmaxf(hv0.z, 0.f), fmaxf(hv0.w, 0.f),
                        fmaxf(hv1.x, 0.f), fmaxf(hv1.y, 0.f), fmaxf(hv1.z, 0.f), fmaxf(hv1.w, 0.f),
                        fmaxf(hv2.x, 0.f), fmaxf(hv2.y, 0.f), fmaxf(hv2.z, 0.f), fmaxf(hv2.w, 0.f),
                        fmaxf(hv3.x, 0.f), fmaxf(hv3.y, 0.f), fmaxf(hv3.z, 0.f), fmaxf(hv3.w, 0.f)};
        float acc[16];
        #pragma unroll
        for (int h = 0; h < 16; ++h) acc[h] = 0.f;
        const float* wr = w + r * 260;
        #pragma unroll
        for (int i = 0; i < 16; ++i) {
            float hi = hs[i];
            const float4* wp = reinterpret_cast<const float4*>(wr + i * 16);
            fma4(acc + 0, hi, wp[0]);
            fma4(acc + 4, hi, wp[1]);
            fma4(acc + 8, hi, wp[2]);
            fma4(acc + 12, hi, wp[3]);
        }
        float* outp = h1 + (size_t)d * HD;
        #pragma unroll
        for (int h = 0; h < 16; ++h) atomicAdd(outp + h, nm * acc[h]);
    }
}

__global__ __launch_bounds__(NTHR) void k_l2_old(const int* __restrict__ esrc, const int* __restrict__ edst,
                                                 const int* __restrict__ erel, const float* __restrict__ enorm,
                                                 const float* __restrict__ h1, const float* __restrict__ Wr2,
                                                 float* __restrict__ h2) {
    __shared__ float w[N_RELS * 132];
    for (int i = threadIdx.x; i < N_RELS * 128; i += NTHR) {
        int r = i >> 7, rest = i & 127;
        w[r * 132 + rest] = Wr2[i];
    }
    __syncthreads();
    for (int e = blockIdx.x * NTHR + threadIdx.x; e < E_TOTAL; e += NBLK * NTHR) {
        int s = esrc[e], d = edst[e], r = erel[e];
        float nm = enorm[e];
        const float4* hp = reinterpret_cast<const float4*>(h1 + (size_t)s * HD);
        float4 hv0 = hp[0], hv1 = hp[1], hv2 = hp[2], hv3 = hp[3];
        float hs[16] = {fmaxf(hv0.x, 0.f), fmaxf(hv0.y, 0.f), fmaxf(hv0.z, 0.f), fmaxf(hv0.w, 0.f),
                        fmaxf(hv1.x, 0.f), fmaxf(hv1.y, 0.f), fmaxf(hv1.z, 0.f), fmaxf(hv1.w, 0.f),
                        fmaxf(hv2.x, 0.f), fmaxf(hv2.y, 0.f), fmaxf(hv2.z, 0.f), fmaxf(hv2.w, 0.f),
                        fmaxf(hv3.x, 0.f), fmaxf(hv3.y, 0.f), fmaxf(hv3.z, 0.f), fmaxf(hv3.w, 0.f)};
        float acc[8];
        #pragma unroll
        for (int h = 0; h < 8; ++h) acc[h] = 0.f;
        const float* wr = w + r * 132;
        #pragma unroll
        for (int i = 0; i < 16; ++i) {
            float hi = hs[i];
            const float4* wp = reinterpret_cast<const float4*>(wr + i * 8);
            fma4(acc + 0, hi, wp[0]);
            fma4(acc + 4, hi, wp[1]);
        }
        float* outp = h2 + (size_t)d * OD;
        #pragma unroll
        for (int h = 0; h < 8; ++h) atomicAdd(outp + h, nm * acc[h]);
    }
}

__global__ __launch_bounds__(NTHR) void k_softmax(const float* __restrict__ h2, float* __restrict__ out) {
    int n = blockIdx.x * NTHR + threadIdx.x;
    if (n >= N_NODES) return;
    const float4* p = reinterpret_cast<const float4*>(h2 + (size_t)n * OD);
    float4 a = p[0], b = p[1];
    float v[8] = {a.x, a.y, a.z, a.w, b.x, b.y, b.z, b.w};
    float m = v[0];
    #pragma unroll
    for (int i = 1; i < 8; ++i) m = fmaxf(m, v[i]);
    float ssum = 0.f;
    #pragma unroll
    for (int i = 0; i < 8; ++i) {
        v[i] = __expf(v[i] - m);
        ssum += v[i];
    }
    float inv = 1.0f / ssum;
    float4* q = reinterpret_cast<float4*>(out + (size_t)n * OD);
    q[0] = make_float4(v[0] * inv, v[1] * inv, v[2] * inv, v[3] * inv);
    q[1] = make_float4(v[4] * inv, v[5] * inv, v[6] * inv, v[7] * inv);
}

// =========================================================================

extern "C" void kernel_launch(void* const* d_in, const int* in_sizes, int n_in,
                              void* d_out, int out_size, void* d_ws, size_t ws_size,
                              hipStream_t stream) {
    const int* esrc = (const int*)d_in[0];
    const int* edst = (const int*)d_in[1];
    const int* erel = (const int*)d_in[2];
    const float* enorm = (const float*)d_in[3];
    const float* W0 = (const float*)d_in[4];
    const float* C0 = (const float*)d_in[5];
    const float* W1 = (const float*)d_in[6];
    const float* C1 = (const float*)d_in[7];
    const float* W2 = (const float*)d_in[8];
    const float* C2 = (const float*)d_in[9];
    const int nsb = (N_NODES + NTHR - 1) / NTHR;  // 391

    if (ws_size >= (size_t)201000000) {
        // ---- Tier A+: dense emb tables; tmp aliases emb (used before emb0) ----
        char* wsb = (char*)d_ws;
        ushort* emb = (ushort*)wsb;                       // 160,000,000 B
        uint2* tmp = (uint2*)wsb;                         //  28,224,000 B (aliases emb)
        uint2* rec = (uint2*)(wsb + 160000000);           //  25,600,000
        float* h0 = (float*)(wsb + 185600000);            //   6,400,000
        float* h1 = (float*)(wsb + 192000000);            //   6,400,000
        float* Wr1 = (float*)(wsb + 198400000);           //      51,200
        float* Wr2 = (float*)(wsb + 198451200);           //      25,600
        int* row_ptr = (int*)(wsb + 198476800);           //     400,004
        int* bhead = (int*)(wsb + 198876804);             //         784
        int* bfinal = (int*)(wsb + 198877588);            //         784

        hipMemsetAsync(bhead, 0, NBKT * sizeof(int), stream);
        k_p1<<<P1_BLOCKS, NTHR, 0, stream>>>(esrc, edst, erel, enorm, bhead, tmp);
        k_bscan<<<1, 256, 0, stream>>>(bhead, bfinal);
        k_p2<<<NBKT, NTHR, 0, stream>>>(tmp, bhead, bfinal, rec, row_ptr);
        k_wr<<<75, NTHR, 0, stream>>>(W1, C1, W2, C2, Wr1, Wr2);

        k_emb0<<<N_NODES * HD / NTHR, NTHR, 0, stream>>>(W0, C0, emb);
        k_g16<<<6250, NTHR, 0, stream>>>(rec, row_ptr, emb, h0);
        k_emb1<<<N_RELS * 391, NTHR, 0, stream>>>(Wr1, h0, emb);
        k_g16<<<6250, NTHR, 0, stream>>>(rec, row_ptr, emb, h1);
        k_emb2<<<N_RELS * 391, NTHR, 0, stream>>>(Wr2, h1, emb);
        k_g8sm<<<6250, NTHR, 0, stream>>>(rec, row_ptr, emb, (float*)d_out);
    } else if (ws_size >= (size_t)92000000) {
        // ---- Tier A: W0t gather L0 + LDS-matvec L1/L2 ----
        char* wsb = (char*)d_ws;
        uint4* W0t = (uint4*)wsb;
        uint2* rec = (uint2*)(wsb + 51200000);
        float* h0 = (float*)(wsb + 76800000);
        float* h1 = (float*)(wsb + 83200000);
        float* Wr1 = (float*)(wsb + 89600000);
        float* Wr2 = (float*)(wsb + 89651200);
        int* cnt = (int*)(wsb + 89676800);
        int* bsum = (int*)(wsb + 90076800);
        int* excl = (int*)(wsb + 90078848);
        int* row_ptr = (int*)(wsb + 90478848);
        int* head = (int*)(wsb + 90878852);

        hipMemsetAsync(cnt, 0, N_NODES * sizeof(int), stream);
        k_transpose<<<(N_NODES * HD) / NTHR, NTHR, 0, stream>>>(W0, W0t);
        k_hist<<<E_TOTAL / NTHR, NTHR, 0, stream>>>(edst, cnt);
        k_scan1<<<nsb, NTHR, 0, stream>>>(cnt, excl, bsum);
        k_scan2<<<1, 512, 0, stream>>>(bsum, nsb);
        k_scan3<<<nsb, NTHR, 0, stream>>>(excl, bsum, row_ptr, head);
        k_scatter<<<E_TOTAL / NTHR, NTHR, 0, stream>>>(esrc, edst, erel, enorm, head, rec);
        k_wr<<<75, NTHR, 0, stream>>>(W1, C1, W2, C2, Wr1, Wr2);

        k_l0s<<<12500, NTHR, 0, stream>>>(rec, row_ptr, C0, W0t, h0);
        k_l1v<<<4096, NTHR, 0, stream>>>(rec, row_ptr, Wr1, h0, h1);
        k_l2v<<<4096, NTHR, 0, stream>>>(rec, row_ptr, Wr2, h1, (float*)d_out);
    } else {
        // ---- Tier B: atomics fallback ----
        float* ws = (float*)d_ws;
        float* h0 = ws;
        float* h1 = ws + 1600000;
        float* h2 = ws + 3200000;
        float* Wr1 = ws + 4000000;
        float* Wr2 = ws + 4012800;

        hipMemsetAsync(h0, 0, (size_t)4000000 * sizeof(float), stream);
        k_wr<<<75, NTHR, 0, stream>>>(W1, C1, W2, C2, Wr1, Wr2);
        k_l0_old<<<NBLK, NTHR, 0, stream>>>(esrc, edst, erel, enorm, W0, C0, h0);
        k_l1_old<<<NBLK, NTHR, 0, stream>>>(esrc, edst, erel, enorm, h0, Wr1, h1);
        k_l2_old<<<NBLK, NTHR, 0, stream>>>(esrc, edst, erel, enorm, h1, Wr2, h2);
        k_softmax<<<nsb, NTHR, 0, stream>>>(h2, (float*)d_out);
    }
}

// Round 5
// 512.098 us; speedup vs baseline: 13.5287x; 1.0601x over previous
//
#include <hip/hip_runtime.h>
#include <cstddef>
#include <cstdint>

#define E_TOTAL 3200000
#define N_NODES 100000
#define N_RELS 50
#define N_BASES 16
#define HD 16
#define OD 8
#define NTHR 256

#define NBKT 196      // coarse buckets: dst >> 9 (512 dsts each)
#define BKT_CAP 18000
#define P1_BLOCKS 256
#define P1_CHUNK 12500
#define NTILE 391     // ceil(100000/256)
#define RPB1 10       // rels per block in k_emb1m (5 groups)

typedef unsigned int u32;

__device__ __forceinline__ float bl16(u32 u) { return __uint_as_float(u << 16); }
__device__ __forceinline__ float bh16(u32 u) { return __uint_as_float(u & 0xffff0000u); }
__device__ __forceinline__ u32 packbf(float x0, float x1) {
    u32 a = __float_as_uint(x0), b = __float_as_uint(x1);
    a = (a + 0x7fffu + ((a >> 16) & 1u)) >> 16;
    b = (b + 0x7fffu + ((b >> 16) & 1u)) >> 16;
    return a | (b << 16);
}

// ---------------- basis-combined dense weights (fp32, in ws) ----------------
__global__ __launch_bounds__(NTHR) void k_wr(const float* __restrict__ W1, const float* __restrict__ C1,
                                             const float* __restrict__ W2, const float* __restrict__ C2,
                                             float* __restrict__ Wr1, float* __restrict__ Wr2) {
    int idx = blockIdx.x * NTHR + threadIdx.x;
    const int n1 = N_RELS * 256;
    if (idx < n1) {
        int r = idx >> 8, io = idx & 255;
        float acc = 0.f;
        #pragma unroll
        for (int b = 0; b < N_BASES; ++b)
            acc = fmaf(C1[r * N_BASES + b], W1[b * 256 + io], acc);
        Wr1[idx] = acc;
    } else if (idx < n1 + N_RELS * 128) {
        int j = idx - n1;
        int r = j >> 7, io = j & 127;
        float acc = 0.f;
        #pragma unroll
        for (int b = 0; b < N_BASES; ++b)
            acc = fmaf(C2[r * N_BASES + b], W2[b * 128 + io], acc);
        Wr2[j] = acc;
    }
}

// ================= two-level dst-sort (write-amplification-free) =================

__global__ __launch_bounds__(NTHR) void k_p1(const int* __restrict__ esrc, const int* __restrict__ edst,
                                             const int* __restrict__ erel, const float* __restrict__ enorm,
                                             int* __restrict__ bhead, uint2* __restrict__ tmp) {
    __shared__ int lcnt[NBKT], lbase[NBKT], lcur[NBKT];
    int tid = threadIdx.x;
    for (int i = tid; i < NBKT; i += NTHR) { lcnt[i] = 0; lcur[i] = 0; }
    __syncthreads();
    int e0 = blockIdx.x * P1_CHUNK;
    for (int i = tid; i < P1_CHUNK; i += NTHR)
        atomicAdd(&lcnt[edst[e0 + i] >> 9], 1);
    __syncthreads();
    for (int i = tid; i < NBKT; i += NTHR)
        lbase[i] = atomicAdd(&bhead[i], lcnt[i]);
    __syncthreads();
    for (int i = tid; i < P1_CHUNK; i += NTHR) {
        int e = e0 + i;
        int d = edst[e];
        int b = d >> 9;
        int pos = b * BKT_CAP + lbase[b] + atomicAdd(&lcur[b], 1);
        tmp[pos] = make_uint2((u32)esrc[e] | ((u32)erel[e] << 17) | ((u32)(d & 511) << 23),
                              __float_as_uint(enorm[e]));
    }
}

__global__ void k_bscan(const int* __restrict__ bhead, int* __restrict__ bfinal) {
    __shared__ int s[256];
    int tid = threadIdx.x;
    int v = (tid < NBKT) ? bhead[tid] : 0;
    s[tid] = v;
    __syncthreads();
    for (int off = 1; off < 256; off <<= 1) {
        int t = (tid >= off) ? s[tid - off] : 0;
        __syncthreads();
        s[tid] += t;
        __syncthreads();
    }
    if (tid < NBKT) bfinal[tid] = s[tid] - v;  // exclusive
}

__global__ __launch_bounds__(NTHR) void k_p2(const uint2* __restrict__ tmp, const int* __restrict__ bhead,
                                             const int* __restrict__ bfinal, uint2* __restrict__ rec,
                                             int* __restrict__ row_ptr) {
    int b = blockIdx.x;
    int cnt = bhead[b];
    int gbase = bfinal[b];
    __shared__ int dcnt[512], dscan[512];
    int tid = threadIdx.x;
    dcnt[tid] = 0;
    dcnt[tid + 256] = 0;
    __syncthreads();
    const uint2* tb = tmp + (size_t)b * BKT_CAP;
    for (int i = tid; i < cnt; i += NTHR)
        atomicAdd(&dcnt[tb[i].x >> 23], 1);
    __syncthreads();
    dscan[tid] = dcnt[tid];
    dscan[tid + 256] = dcnt[tid + 256];
    __syncthreads();
    for (int off = 1; off < 512; off <<= 1) {
        int v0 = (tid >= off) ? dscan[tid - off] : 0;
        int v1 = (tid + 256 >= off) ? dscan[tid + 256 - off] : 0;
        __syncthreads();
        dscan[tid] += v0;
        dscan[tid + 256] += v1;
        __syncthreads();
    }
    int d0 = b << 9;
    #pragma unroll
    for (int k = 0; k < 2; ++k) {
        int dl = tid + k * 256;
        int excl = gbase + dscan[dl] - dcnt[dl];
        int d = d0 + dl;
        if (d < N_NODES) row_ptr[d] = excl;
        dscan[dl] = excl;
    }
    if (b == NBKT - 1 && tid == 0) row_ptr[N_NODES] = E_TOTAL;
    __syncthreads();
    for (int i = tid; i < cnt; i += NTHR) {
        uint2 t = tb[i];
        int pos = atomicAdd(&dscan[t.x >> 23], 1);
        rec[pos] = make_uint2(t.x & 0x7FFFFFu, t.y);
    }
}

// ================= dense embedding tables =================

// emb0[r][n][h] = sum_b C0[r,b]*W0[b,n,h], bf16.
__global__ __launch_bounds__(NTHR) void k_emb0(const float* __restrict__ W0, const float* __restrict__ C0,
                                               ushort* __restrict__ emb) {
    int t = threadIdx.x;
    size_t base = (size_t)blockIdx.x * 256 + t;  // n*16+h
    float w[16];
    #pragma unroll
    for (int b = 0; b < 16; ++b) w[b] = W0[(size_t)b * (N_NODES * HD) + base];
    __shared__ float c[N_RELS * 16];
    for (int i = t; i < N_RELS * 16; i += NTHR) c[i] = C0[i];
    __syncthreads();
    for (int r = 0; r < N_RELS; ++r) {
        const float* cr = c + r * 16;
        float v = 0.f;
        #pragma unroll
        for (int b = 0; b < 16; ++b) v = fmaf(cr[b], w[b], v);
        u32 x = __float_as_uint(v);
        x = (x + 0x7fffu + ((x >> 16) & 1u)) >> 16;
        emb[(size_t)r * (N_NODES * HD) + base] = (ushort)x;
    }
}

// gather-accumulate 16-dim bf16 rows by (rel,src), relu-fused, fp32 out.
__global__ __launch_bounds__(NTHR) void k_g16(const uint2* __restrict__ rec, const int* __restrict__ row_ptr,
                                              const ushort* __restrict__ tbl, float* __restrict__ out) {
    int lane = threadIdx.x & 63;
    int g = lane >> 3, l = lane & 7;
    int wave = (blockIdx.x * NTHR + threadIdx.x) >> 6;
    int nw = (gridDim.x * NTHR) >> 6;
    for (int d = wave; d < N_NODES; d += nw) {
        int s0 = row_ptr[d], s1 = row_ptr[d + 1];
        float a0 = 0.f, a1 = 0.f;
        for (int j = s0 + g; j < s1; j += 8) {
            uint2 rc = rec[j];
            int src = rc.x & 0x1FFFF;
            int rel = rc.x >> 17;
            float nm = __uint_as_float(rc.y);
            u32 q = *(const u32*)(tbl + ((size_t)rel * N_NODES + src) * HD + l * 2);
            a0 = fmaf(nm, bl16(q), a0);
            a1 = fmaf(nm, bh16(q), a1);
        }
        a0 += __shfl_xor(a0, 8);  a1 += __shfl_xor(a1, 8);
        a0 += __shfl_xor(a0, 16); a1 += __shfl_xor(a1, 16);
        a0 += __shfl_xor(a0, 32); a1 += __shfl_xor(a1, 32);
        if (lane < 8)
            *(float2*)(out + (size_t)d * HD + l * 2) = make_float2(fmaxf(a0, 0.f), fmaxf(a1, 0.f));
    }
}

// emb1[r][n][o] = sum_i h[n,i]*Wr1[r,i,o], bf16 out.
// Node-tile-major: block loads its 256-node h-tile ONCE (registers), loops RPB1 rels.
__global__ __launch_bounds__(NTHR) void k_emb1m(const float* __restrict__ Wr1, const float* __restrict__ h,
                                                ushort* __restrict__ emb) {
    int grp = blockIdx.x / NTILE;   // rel group: [grp*RPB1, grp*RPB1+RPB1)
    int tile = blockIdx.x % NTILE;
    __shared__ float w[RPB1 * 256];  // 10 KB
    for (int i = threadIdx.x; i < RPB1 * 256; i += NTHR)
        w[i] = Wr1[grp * (RPB1 * 256) + i];
    __syncthreads();
    int n = tile * NTHR + threadIdx.x;
    if (n >= N_NODES) return;
    const float4* hp = (const float4*)(h + (size_t)n * HD);
    float4 a0 = hp[0], a1 = hp[1], a2 = hp[2], a3 = hp[3];
    float hv[16] = {a0.x, a0.y, a0.z, a0.w, a1.x, a1.y, a1.z, a1.w,
                    a2.x, a2.y, a2.z, a2.w, a3.x, a3.y, a3.z, a3.w};
    for (int rr = 0; rr < RPB1; ++rr) {
        const float* wr = w + rr * 256;
        float acc[16];
        #pragma unroll
        for (int o = 0; o < 16; ++o) acc[o] = 0.f;
        #pragma unroll
        for (int i = 0; i < 16; ++i) {
            const float4* wp = (const float4*)(wr + i * 16);  // uniform -> LDS broadcast
            float4 w0 = wp[0], w1 = wp[1], w2 = wp[2], w3 = wp[3];
            float hi = hv[i];
            acc[0] = fmaf(hi, w0.x, acc[0]);   acc[1] = fmaf(hi, w0.y, acc[1]);
            acc[2] = fmaf(hi, w0.z, acc[2]);   acc[3] = fmaf(hi, w0.w, acc[3]);
            acc[4] = fmaf(hi, w1.x, acc[4]);   acc[5] = fmaf(hi, w1.y, acc[5]);
            acc[6] = fmaf(hi, w1.z, acc[6]);   acc[7] = fmaf(hi, w1.w, acc[7]);
            acc[8] = fmaf(hi, w2.x, acc[8]);   acc[9] = fmaf(hi, w2.y, acc[9]);
            acc[10] = fmaf(hi, w2.z, acc[10]); acc[11] = fmaf(hi, w2.w, acc[11]);
            acc[12] = fmaf(hi, w3.x, acc[12]); acc[13] = fmaf(hi, w3.y, acc[13]);
            acc[14] = fmaf(hi, w3.z, acc[14]); acc[15] = fmaf(hi, w3.w, acc[15]);
        }
        u32 p[8];
        #pragma unroll
        for (int k = 0; k < 8; ++k) p[k] = packbf(acc[2 * k], acc[2 * k + 1]);
        uint4* op = (uint4*)(emb + ((size_t)(grp * RPB1 + rr) * N_NODES + n) * HD);
        op[0] = make_uint4(p[0], p[1], p[2], p[3]);
        op[1] = make_uint4(p[4], p[5], p[6], p[7]);
    }
}

// L2 + fused softmax: per-edge matvec, bf16 weights in LDS. 8 edge-groups x 8 out-dims.
// LDS [r][o][8 u32], o-stride 12 (<=2-way in-group conflicts), r-stride 100.
__global__ __launch_bounds__(NTHR) void k_l2v(const uint2* __restrict__ rec, const int* __restrict__ row_ptr,
                                              const float* __restrict__ Wr2, const float* __restrict__ h1,
                                              float* __restrict__ out) {
    __shared__ u32 wl[N_RELS * 100];  // 20 KB -> 8 blocks/CU
    for (int idx = threadIdx.x; idx < N_RELS * 64; idx += NTHR) {
        int r = idx >> 6, rem = idx & 63, o = rem >> 3, p = rem & 7;
        wl[r * 100 + o * 12 + p] = packbf(Wr2[r * 128 + (2 * p) * 8 + o],
                                          Wr2[r * 128 + (2 * p + 1) * 8 + o]);
    }
    __syncthreads();
    int lane = threadIdx.x & 63;
    int g = lane >> 3, o = lane & 7;
    int wave = (blockIdx.x * NTHR + threadIdx.x) >> 6;
    int nw = (gridDim.x * NTHR) >> 6;
    const u32* wol = wl + o * 12;
    for (int d = wave; d < N_NODES; d += nw) {
        int s0 = row_ptr[d], s1 = row_ptr[d + 1];
        float acc = 0.f;
        for (int j = s0 + g; j < s1; j += 8) {
            uint2 rc = rec[j];
            int src = rc.x & 0x1FFFF;
            int rel = rc.x >> 17;
            float nm = __uint_as_float(rc.y);
            const float4* hp = (const float4*)(h1 + (size_t)src * HD);  // uniform in 8-lane group
            float4 a0 = hp[0], a1 = hp[1], a2 = hp[2], a3 = hp[3];
            const uint4* wp = (const uint4*)(wol + rel * 100);
            uint4 q0 = wp[0], q1 = wp[1];
            float m = bl16(q0.x) * a0.x + bh16(q0.x) * a0.y + bl16(q0.y) * a0.z + bh16(q0.y) * a0.w +
                      bl16(q0.z) * a1.x + bh16(q0.z) * a1.y + bl16(q0.w) * a1.z + bh16(q0.w) * a1.w +
                      bl16(q1.x) * a2.x + bh16(q1.x) * a2.y + bl16(q1.y) * a2.z + bh16(q1.y) * a2.w +
                      bl16(q1.z) * a3.x + bh16(q1.z) * a3.y + bl16(q1.w) * a3.z + bh16(q1.w) * a3.w;
            acc = fmaf(nm, m, acc);
        }
        acc += __shfl_xor(acc, 8);
        acc += __shfl_xor(acc, 16);
        acc += __shfl_xor(acc, 32);
        float mx = acc;
        mx = fmaxf(mx, __shfl_xor(mx, 1));
        mx = fmaxf(mx, __shfl_xor(mx, 2));
        mx = fmaxf(mx, __shfl_xor(mx, 4));
        float ex = __expf(acc - mx);
        float sm = ex;
        sm += __shfl_xor(sm, 1);
        sm += __shfl_xor(sm, 2);
        sm += __shfl_xor(sm, 4);
        if (lane < 8) out[(size_t)d * OD + o] = ex / sm;
    }
}

// ======= TIER B fallback (atomics, 16.1 MB) =======
#define NBLK 2560

__device__ __forceinline__ void fma4(float* acc, float c, float4 w) {
    acc[0] = fmaf(c, w.x, acc[0]);
    acc[1] = fmaf(c, w.y, acc[1]);
    acc[2] = fmaf(c, w.z, acc[2]);
    acc[3] = fmaf(c, w.w, acc[3]);
}

__global__ __launch_bounds__(NTHR) void k_l0_old(const int* __restrict__ esrc, const int* __restrict__ edst,
                                                 const int* __restrict__ erel, const float* __restrict__ enorm,
                                                 const float* __restrict__ W0, const float* __restrict__ C0,
                                                 float* __restrict__ h0) {
    for (int e = blockIdx.x * NTHR + threadIdx.x; e < E_TOTAL; e += NBLK * NTHR) {
        int s = esrc[e], d = edst[e], r = erel[e];
        float nm = enorm[e];
        const float4* cp = reinterpret_cast<const float4*>(C0 + r * N_BASES);
        float4 c0 = cp[0], c1 = cp[1], c2 = cp[2], c3 = cp[3];
        float coef[16] = {c0.x, c0.y, c0.z, c0.w, c1.x, c1.y, c1.z, c1.w,
                          c2.x, c2.y, c2.z, c2.w, c3.x, c3.y, c3.z, c3.w};
        float acc[16];
        #pragma unroll
        for (int h = 0; h < 16; ++h) acc[h] = 0.f;
        const float* wbase = W0 + (size_t)s * HD;
        #pragma unroll
        for (int b = 0; b < N_BASES; ++b) {
            const float4* wp = reinterpret_cast<const float4*>(wbase + (size_t)b * (N_NODES * HD));
            float cb = coef[b];
            fma4(acc + 0, cb, wp[0]);
            fma4(acc + 4, cb, wp[1]);
            fma4(acc + 8, cb, wp[2]);
            fma4(acc + 12, cb, wp[3]);
        }
        float* outp = h0 + (size_t)d * HD;
        #pragma unroll
        for (int h = 0; h < 16; ++h) atomicAdd(outp + h, nm * acc[h]);
    }
}

__global__ __launch_bounds__(NTHR) void k_l1_old(const int* __restrict__ esrc, const int* __restrict__ edst,
                                                 const int* __restrict__ erel, const float* __restrict__ enorm,
                                                 const float* __restrict__ h0, const float* __restrict__ Wr1,
                                                 float* __restrict__ h1) {
    __shared__ float w[N_RELS * 260];
    for (int i = threadIdx.x; i < N_RELS * 256; i += NTHR) {
        int r = i >> 8, rest = i & 255;
        w[r * 260 + rest] = Wr1[i];
    }
    __syncthreads();
    for (int e = blockIdx.x * NTHR + threadIdx.x; e < E_TOTAL; e += NBLK * NTHR) {
        int s = esrc[e], d = edst[e], r = erel[e];
        float nm = enorm[e];
        const float4* hp = reinterpret_cast<const float4*>(h0 + (size_t)s * HD);
        float4 hv0 = hp[0], hv1 = hp[1], hv2 = hp[2], hv3 = hp[3];
        float hs[16] = {fmaxf(hv0.x, 0.f), fmaxf(hv0.y, 0.f), fmaxf(hv0.z, 0.f), fmaxf(hv0.w, 0.f),
                        fmaxf(hv1.x, 0.f), fmaxf(hv1.y, 0.f), fmaxf(hv1.z, 0.f), fmaxf(hv1.w, 0.f),
                        fmaxf(hv2.x, 0.f), fmaxf(hv2.y, 0.f), fmaxf(hv2.z, 0.f), fmaxf(hv2.w, 0.f),
                        fmaxf(hv3.x, 0.f), fmaxf(hv3.y, 0.f), fmaxf(hv3.z, 0.f), fmaxf(hv3.w, 0.f)};
        float acc[16];
        #pragma unroll
        for (int h = 0; h < 16; ++h) acc[h] = 0.f;
        const float* wr = w + r * 260;
        #pragma unroll
        for (int i = 0; i < 16; ++i) {
            float hi = hs[i];
            const float4* wp = reinterpret_cast<const float4*>(wr + i * 16);
            fma4(acc + 0, hi, wp[0]);
            fma4(acc + 4, hi, wp[1]);
            fma4(acc + 8, hi, wp[2]);
            fma4(acc + 12, hi, wp[3]);
        }
        float* outp = h1 + (size_t)d * HD;
        #pragma unroll
        for (int h = 0; h < 16; ++h) atomicAdd(outp + h, nm * acc[h]);
    }
}

__global__ __launch_bounds__(NTHR) void k_l2_old(const int* __restrict__ esrc, const int* __restrict__ edst,
                                                 const int* __restrict__ erel, const float* __restrict__ enorm,
                                                 const float* __restrict__ h1, const float* __restrict__ Wr2,
                                                 float* __restrict__ h2) {
    __shared__ float w[N_RELS * 132];
    for (int i = threadIdx.x; i < N_RELS * 128; i += NTHR) {
        int r = i >> 7, rest = i & 127;
        w[r * 132 + rest] = Wr2[i];
    }
    __syncthreads();
    for (int e = blockIdx.x * NTHR + threadIdx.x; e < E_TOTAL; e += NBLK * NTHR) {
        int s = esrc[e], d = edst[e], r = erel[e];
        float nm = enorm[e];
        const float4* hp = reinterpret_cast<const float4*>(h1 + (size_t)s * HD);
        float4 hv0 = hp[0], hv1 = hp[1], hv2 = hp[2], hv3 = hp[3];
        float hs[16] = {fmaxf(hv0.x, 0.f), fmaxf(hv0.y, 0.f), fmaxf(hv0.z, 0.f), fmaxf(hv0.w, 0.f),
                        fmaxf(hv1.x, 0.f), fmaxf(hv1.y, 0.f), fmaxf(hv1.z, 0.f), fmaxf(hv1.w, 0.f),
                        fmaxf(hv2.x, 0.f), fmaxf(hv2.y, 0.f), fmaxf(hv2.z, 0.f), fmaxf(hv2.w, 0.f),
                        fmaxf(hv3.x, 0.f), fmaxf(hv3.y, 0.f), fmaxf(hv3.z, 0.f), fmaxf(hv3.w, 0.f)};
        float acc[8];
        #pragma unroll
        for (int h = 0; h < 8; ++h) acc[h] = 0.f;
        const float* wr = w + r * 132;
        #pragma unroll
        for (int i = 0; i < 16; ++i) {
            float hi = hs[i];
            const float4* wp = reinterpret_cast<const float4*>(wr + i * 8);
            fma4(acc + 0, hi, wp[0]);
            fma4(acc + 4, hi, wp[1]);
        }
        float* outp = h2 + (size_t)d * OD;
        #pragma unroll
        for (int h = 0; h < 8; ++h) atomicAdd(outp + h, nm * acc[h]);
    }
}

__global__ __launch_bounds__(NTHR) void k_softmax(const float* __restrict__ h2, float* __restrict__ out) {
    int n = blockIdx.x * NTHR + threadIdx.x;
    if (n >= N_NODES) return;
    const float4* p = reinterpret_cast<const float4*>(h2 + (size_t)n * OD);
    float4 a = p[0], b = p[1];
    float v[8] = {a.x, a.y, a.z, a.w, b.x, b.y, b.z, b.w};
    float m = v[0];
    #pragma unroll
    for (int i = 1; i < 8; ++i) m = fmaxf(m, v[i]);
    float ssum = 0.f;
    #pragma unroll
    for (int i = 0; i < 8; ++i) {
        v[i] = __expf(v[i] - m);
        ssum += v[i];
    }
    float inv = 1.0f / ssum;
    float4* q = reinterpret_cast<float4*>(out + (size_t)n * OD);
    q[0] = make_float4(v[0] * inv, v[1] * inv, v[2] * inv, v[3] * inv);
    q[1] = make_float4(v[4] * inv, v[5] * inv, v[6] * inv, v[7] * inv);
}

// =========================================================================

extern "C" void kernel_launch(void* const* d_in, const int* in_sizes, int n_in,
                              void* d_out, int out_size, void* d_ws, size_t ws_size,
                              hipStream_t stream) {
    const int* esrc = (const int*)d_in[0];
    const int* edst = (const int*)d_in[1];
    const int* erel = (const int*)d_in[2];
    const float* enorm = (const float*)d_in[3];
    const float* W0 = (const float*)d_in[4];
    const float* C0 = (const float*)d_in[5];
    const float* W1 = (const float*)d_in[6];
    const float* C1 = (const float*)d_in[7];
    const float* W2 = (const float*)d_in[8];
    const float* C2 = (const float*)d_in[9];
    const int nsb = (N_NODES + NTHR - 1) / NTHR;  // 391

    if (ws_size >= (size_t)201000000) {
        char* wsb = (char*)d_ws;
        ushort* emb = (ushort*)wsb;                       // 160,000,000 B
        uint2* tmp = (uint2*)wsb;                         //  28,224,000 B (aliases emb; used before emb0)
        uint2* rec = (uint2*)(wsb + 160000000);           //  25,600,000
        float* h0 = (float*)(wsb + 185600000);            //   6,400,000
        float* h1 = (float*)(wsb + 192000000);            //   6,400,000
        float* Wr1 = (float*)(wsb + 198400000);           //      51,200
        float* Wr2 = (float*)(wsb + 198451200);           //      25,600
        int* row_ptr = (int*)(wsb + 198476800);           //     400,004
        int* bhead = (int*)(wsb + 198876804);             //         784
        int* bfinal = (int*)(wsb + 198877588);            //         784

        hipMemsetAsync(bhead, 0, NBKT * sizeof(int), stream);
        k_p1<<<P1_BLOCKS, NTHR, 0, stream>>>(esrc, edst, erel, enorm, bhead, tmp);
        k_bscan<<<1, 256, 0, stream>>>(bhead, bfinal);
        k_p2<<<NBKT, NTHR, 0, stream>>>(tmp, bhead, bfinal, rec, row_ptr);
        k_wr<<<75, NTHR, 0, stream>>>(W1, C1, W2, C2, Wr1, Wr2);

        k_emb0<<<N_NODES * HD / NTHR, NTHR, 0, stream>>>(W0, C0, emb);
        k_g16<<<6250, NTHR, 0, stream>>>(rec, row_ptr, emb, h0);
        k_emb1m<<<5 * NTILE, NTHR, 0, stream>>>(Wr1, h0, emb);
        k_g16<<<6250, NTHR, 0, stream>>>(rec, row_ptr, emb, h1);
        k_l2v<<<4096, NTHR, 0, stream>>>(rec, row_ptr, Wr2, h1, (float*)d_out);
    } else {
        // ---- Tier B: atomics fallback ----
        float* ws = (float*)d_ws;
        float* h0 = ws;
        float* h1 = ws + 1600000;
        float* h2 = ws + 3200000;
        float* Wr1 = ws + 4000000;
        float* Wr2 = ws + 4012800;

        hipMemsetAsync(h0, 0, (size_t)4000000 * sizeof(float), stream);
        k_wr<<<75, NTHR, 0, stream>>>(W1, C1, W2, C2, Wr1, Wr2);
        k_l0_old<<<NBLK, NTHR, 0, stream>>>(esrc, edst, erel, enorm, W0, C0, h0);
        k_l1_old<<<NBLK, NTHR, 0, stream>>>(esrc, edst, erel, enorm, h0, Wr1, h1);
        k_l2_old<<<NBLK, NTHR, 0, stream>>>(esrc, edst, erel, enorm, h1, Wr2, h2);
        k_softmax<<<nsb, NTHR, 0, stream>>>(h2, (float*)d_out);
    }
}